// Round 4
// baseline (3025.776 us; speedup 1.0000x reference)
//
#include <hip/hip_runtime.h>
#include <math.h>

typedef unsigned short u16;
typedef unsigned int u32;
typedef __bf16 bf16x8 __attribute__((ext_vector_type(8)));
typedef float f32x4 __attribute__((ext_vector_type(4)));
typedef u16 us8 __attribute__((ext_vector_type(8)));

#define TOKENS 1024
#define DIM 256
#define SEQ 512

// ---------- helpers ----------

__device__ __forceinline__ u16 f2bf(float f) {
  u32 x = __float_as_uint(f);
  x += 0x7fffu + ((x >> 16) & 1u);
  return (u16)(x >> 16);
}

// silu + 8 cubic B-spline bases (uniform extended grid g[j] = (j-3)*0.4f - 1.0f)
__device__ __forceinline__ void expand9(float x, u16* sil, us8* u) {
  float sig = 1.0f / (1.0f + expf(-x));
  *sil = f2bf(x * sig);
  float bs[11];
#pragma unroll
  for (int j = 0; j < 11; j++) {
    float gj  = (float)(j - 3) * 0.4f - 1.0f;
    float gj1 = (float)(j - 2) * 0.4f - 1.0f;
    bs[j] = (x >= gj && x < gj1) ? 1.0f : 0.0f;
  }
#pragma unroll
  for (int k = 1; k <= 3; k++) {
#pragma unroll
    for (int j = 0; j < 10; j++) {
      if (j + k < 11) {
        float gj   = (float)(j - 3) * 0.4f - 1.0f;
        float gj1  = (float)(j - 2) * 0.4f - 1.0f;
        float gjk  = (float)(j + k - 3) * 0.4f - 1.0f;
        float gjk1 = (float)(j + k - 2) * 0.4f - 1.0f;
        bs[j] = (x - gj) / (gjk - gj) * bs[j] + (gjk1 - x) / (gjk1 - gj1) * bs[j + 1];
      }
    }
  }
#pragma unroll
  for (int c = 0; c < 8; c++) (*u)[c] = f2bf(bs[c]);
}

// 256-thread block sum (4 waves of 64)
__device__ __forceinline__ float block_sum_256(float v) {
  __shared__ float red[4];
  int t = threadIdx.x, lane = t & 63, wid = t >> 6;
#pragma unroll
  for (int o = 32; o > 0; o >>= 1) v += __shfl_down(v, o, 64);
  __syncthreads();
  if (lane == 0) red[wid] = v;
  __syncthreads();
  return red[0] + red[1] + red[2] + red[3];
}

// ---------- embedding + LN (eps 1e-12) + expand ----------

__global__ void embed_ln_x(const int* __restrict__ ids, const float* __restrict__ wemb,
                           const float* __restrict__ tt, const float* __restrict__ pe,
                           const float* __restrict__ g, const float* __restrict__ bta,
                           float* __restrict__ xout, u16* __restrict__ Xe) {
  int row = blockIdx.x, t = threadIdx.x;
  int id = ids[row];
  float v = wemb[(size_t)id * DIM + t] + tt[DIM + t] + pe[DIM + t];
  float mu = block_sum_256(v) * (1.0f / 256.0f);
  float d = v - mu;
  float var = block_sum_256(d * d) * (1.0f / 256.0f);
  float y = d * rsqrtf(var + 1e-12f) * g[t] + bta[t];
  xout[(size_t)row * DIM + t] = y;
  size_t base = (size_t)row * 2304;
  u16 s; us8 u;
  expand9(y, &s, &u);
  Xe[base + t] = s;
  *(us8*)(Xe + base + 256 + (size_t)t * 8) = u;
}

// ---------- (sum of nsum partials) [+gelu] [+res] + LN + expand ----------

__global__ void add_ln_x(const float* __restrict__ a, int nsum, int sstride,
                         const float* __restrict__ res,
                         const float* __restrict__ g, const float* __restrict__ bta,
                         float eps, int dogelu,
                         float* __restrict__ xout, u16* __restrict__ Xe) {
  int row = blockIdx.x, t = threadIdx.x;
  int idx = row * 256 + t;
  float v = 0.f;
  for (int s = 0; s < nsum; s++) v += a[(size_t)s * sstride + idx];
  if (dogelu) v = 0.5f * v * (1.0f + erff(v * 0.70710678118654752f));
  if (res) v += res[idx];
  float mu = block_sum_256(v) * (1.0f / 256.0f);
  float d = v - mu;
  float var = block_sum_256(d * d) * (1.0f / 256.0f);
  float y = d * rsqrtf(var + eps);
  if (g) y = y * g[t] + bta[t];
  xout[idx] = y;
  size_t base = (size_t)row * 2304;
  u16 s16; us8 u;
  expand9(y, &s16, &u);
  Xe[base + t] = s16;
  *(us8*)(Xe + base + 256 + (size_t)t * 8) = u;
}

// ---------- all-weight pack in one dispatch ----------

struct PackA {
  const float* b[8];
  const float* s[8];
  unsigned long long off[8];   // elem offset into Wc
  long long cum[9];            // cumulative element counts
  int shift[8];
};

__global__ void pack_all(PackA pa, u16* __restrict__ Wc) {
  long idx = (long)blockIdx.x * 256 + threadIdx.x;
  if (idx >= pa.cum[8]) return;
  int s = 0;
#pragma unroll
  for (int i = 1; i < 8; i++) if (idx >= pa.cum[i]) s = i;
  long local = idx - pa.cum[s];
  int shift = pa.shift[s];
  int infeat = 1 << shift;
  long r = local >> shift;
  int i = (int)(local & (infeat - 1));
  int K = infeat * 9;
  u16* dst = Wc + pa.off[s];
  dst[(size_t)r * K + i] = f2bf(pa.b[s][local]);
  const float* sp = pa.s[s] + (size_t)local * 8;
  float4 f0 = *(const float4*)sp;
  float4 f1v = *(const float4*)(sp + 4);
  us8 u;
  u[0] = f2bf(f0.x); u[1] = f2bf(f0.y); u[2] = f2bf(f0.z); u[3] = f2bf(f0.w);
  u[4] = f2bf(f1v.x); u[5] = f2bf(f1v.y); u[6] = f2bf(f1v.z); u[7] = f2bf(f1v.w);
  *(us8*)(dst + (size_t)r * K + infeat + (size_t)i * 8) = u;
}

// ---------- GEMM (packed bf16 weights): C[1024,N] = A[1024,K] @ W[N,K]^T ----------
// XCD-contiguous remap, XOR-swizzled LDS, register-prefetch pipeline.
// blockIdx.z = K-split slice (kchunk each); partial C at z*TOKENS*N.
// EPI: 0 = f32 store; 1 = relu + KAN-expand into XeOut (ld = infOut*9).
// MINW = __launch_bounds__ min-waves/EU (1 for big tiles: prevents VGPR-cap spill).

template <int BM, int BN, int EPI, int MINW>
__global__ __launch_bounds__(256, MINW)
void gemm_b16(const u16* __restrict__ A,
              const u16* __restrict__ W0, const u16* __restrict__ W1, const u16* __restrict__ W2,
              int nper, int N, int K, int kchunk,
              float* __restrict__ C, u16* __restrict__ XeOut, int infOut) {
  constexpr int BK = 64;
  constexpr int FM = BM / 32, FN = BN / 32;
  constexpr int NA = BM / 32, NB = BN / 32;
  __shared__ u16 As[BM * BK];
  __shared__ u16 Bs[BN * BK];
  const int gx = gridDim.x;
  const int nwg = gx * gridDim.y;
  int g = blockIdx.y * gx + blockIdx.x;
  int lin = g;
  if ((nwg & 7) == 0) lin = (g & 7) * (nwg >> 3) + (g >> 3);
  const int m0 = (lin % gx) * BM;
  const int n0 = (lin / gx) * BN;
  const int z = blockIdx.z;
  const int kbeg = z * kchunk;
  const int kend = (kbeg + kchunk < K) ? kbeg + kchunk : K;
  const int t = threadIdx.x;
  const int lane = t & 63, wid = t >> 6;
  const int wm = (wid >> 1) * (BM / 2), wn = (wid & 1) * (BN / 2);
  const int proj = n0 / nper;
  const u16* W = proj == 0 ? W0 : (proj == 1 ? W1 : W2);
  const int onb = n0 - proj * nper;

  f32x4 acc[FM][FN];
#pragma unroll
  for (int i = 0; i < FM; i++)
#pragma unroll
    for (int j = 0; j < FN; j++) acc[i][j] = (f32x4){0.f, 0.f, 0.f, 0.f};

  const int frow = lane & 15;
  const int cgrp = lane >> 4;

  uint4 ra[NA], rb[NB];
  auto ldg = [&](int k0) {
#pragma unroll
    for (int c = 0; c < NA; c++) {
      int e = c * 256 + t, r = e >> 3, ch = e & 7;
      ra[c] = *(const uint4*)(A + (size_t)(m0 + r) * K + k0 + ch * 8);
    }
#pragma unroll
    for (int c = 0; c < NB; c++) {
      int e = c * 256 + t, r = e >> 3, ch = e & 7;
      rb[c] = *(const uint4*)(W + (size_t)(onb + r) * K + k0 + ch * 8);
    }
  };

  ldg(kbeg);
  for (int k0 = kbeg; k0 < kend; k0 += BK) {
#pragma unroll
    for (int c = 0; c < NA; c++) {
      int e = c * 256 + t, r = e >> 3, ch = e & 7;
      *(uint4*)(&As[r * BK + ((ch ^ (r & 7)) << 3)]) = ra[c];
    }
#pragma unroll
    for (int c = 0; c < NB; c++) {
      int e = c * 256 + t, r = e >> 3, ch = e & 7;
      *(uint4*)(&Bs[r * BK + ((ch ^ (r & 7)) << 3)]) = rb[c];
    }
    __syncthreads();
    if (k0 + BK < kend) ldg(k0 + BK);          // prefetch next tile
#pragma unroll
    for (int half = 0; half < 2; half++) {
      const int ch = half * 4 + cgrp;
      bf16x8 af[FM], bfr[FN];
#pragma unroll
      for (int i = 0; i < FM; i++) {
        int rr = wm + i * 16 + frow;
        af[i] = *reinterpret_cast<const bf16x8*>(&As[rr * BK + ((ch ^ (rr & 7)) << 3)]);
      }
#pragma unroll
      for (int j = 0; j < FN; j++) {
        int rr = wn + j * 16 + frow;
        bfr[j] = *reinterpret_cast<const bf16x8*>(&Bs[rr * BK + ((ch ^ (rr & 7)) << 3)]);
      }
#pragma unroll
      for (int i = 0; i < FM; i++)
#pragma unroll
        for (int j = 0; j < FN; j++)
          acc[i][j] = __builtin_amdgcn_mfma_f32_16x16x32_bf16(af[i], bfr[j], acc[i][j], 0, 0, 0);
    }
    __syncthreads();
  }

  const int crow = (lane >> 4) * 4;
  const int ccol = lane & 15;
  if (EPI == 0) {
    float* Cz = C + (size_t)z * TOKENS * N;
#pragma unroll
    for (int i = 0; i < FM; i++)
#pragma unroll
      for (int j = 0; j < FN; j++) {
        int row = m0 + wm + i * 16 + crow;
        int col = n0 + wn + j * 16 + ccol;
#pragma unroll
        for (int r = 0; r < 4; r++)
          Cz[(size_t)(row + r) * N + col] = acc[i][j][r];
      }
  } else {
    const int ldXe = infOut * 9;
#pragma unroll
    for (int i = 0; i < FM; i++)
#pragma unroll
      for (int j = 0; j < FN; j++) {
        int row0 = m0 + wm + i * 16 + crow;
        int col = n0 + wn + j * 16 + ccol;
#pragma unroll
        for (int r = 0; r < 4; r++) {
          float y = fmaxf(acc[i][j][r], 0.0f);     // relu
          u16 s; us8 u;
          expand9(y, &s, &u);
          size_t base = (size_t)(row0 + r) * ldXe;
          XeOut[base + col] = s;
          *(us8*)(XeOut + base + infOut + (size_t)col * 8) = u;
        }
      }
  }
}

// ---------- fused attention: QK^T + softmax + PV + KAN-expand (P stays in LDS) ----------

__global__ void attn_fused(const float* __restrict__ qkv, u16* __restrict__ Xe) {
  int bh = blockIdx.x, b = bh >> 2, h = bh & 3;
  int s0 = blockIdx.y * 16;
  int t = threadIdx.x;
  __shared__ float Qs[16][64];
  __shared__ float Ks[16][65];
  __shared__ float Ss[16][513];
  __shared__ float red[16][17];
  __shared__ float Vs[32][65];
#pragma unroll
  for (int c = 0; c < 4; c++) {
    int e = c * 256 + t, r = e >> 6, d = e & 63;
    Qs[r][d] = qkv[(size_t)(b * SEQ + s0 + r) * 768 + h * 64 + d];
  }
  int r = t >> 4, cc = t & 15;
  for (int kc = 0; kc < SEQ; kc += 16) {
    __syncthreads();
#pragma unroll
    for (int c = 0; c < 4; c++) {
      int e = c * 256 + t, rr = e >> 6, d = e & 63;
      Ks[rr][d] = qkv[(size_t)(b * SEQ + kc + rr) * 768 + 256 + h * 64 + d];
    }
    __syncthreads();
    float acc = 0.f;
#pragma unroll
    for (int d = 0; d < 64; d++) acc += Qs[r][d] * Ks[cc][d];
    Ss[r][kc + cc] = acc * 0.125f;
  }
  __syncthreads();
  float mx = -3.4e38f;
  for (int j = cc; j < SEQ; j += 16) mx = fmaxf(mx, Ss[r][j]);
  red[r][cc] = mx;
  __syncthreads();
  if (cc == 0) {
    float m = red[r][0];
#pragma unroll
    for (int j = 1; j < 16; j++) m = fmaxf(m, red[r][j]);
    red[r][16] = m;
  }
  __syncthreads();
  mx = red[r][16];
  float sm = 0.f;
  for (int j = cc; j < SEQ; j += 16) {
    float e = expf(Ss[r][j] - mx);
    Ss[r][j] = e;
    sm += e;
  }
  __syncthreads();
  red[r][cc] = sm;
  __syncthreads();
  if (cc == 0) {
    float s = 0.f;
#pragma unroll
    for (int j = 0; j < 16; j++) s += red[r][j];
    red[r][16] = s;
  }
  __syncthreads();
  float inv = 1.0f / red[r][16];
  for (int j = cc; j < SEQ; j += 16) Ss[r][j] *= inv;
  // PV
  int dd = cc * 4;
  float a[4] = {0.f, 0.f, 0.f, 0.f};
  for (int kc = 0; kc < SEQ; kc += 32) {
    __syncthreads();
#pragma unroll
    for (int c = 0; c < 8; c++) {
      int e = c * 256 + t, rr = e >> 6, d = e & 63;
      Vs[rr][d] = qkv[(size_t)(b * SEQ + kc + rr) * 768 + 512 + h * 64 + d];
    }
    __syncthreads();
#pragma unroll
    for (int kk = 0; kk < 32; kk++) {
      float p = Ss[r][kc + kk];
      a[0] += p * Vs[kk][dd + 0];
      a[1] += p * Vs[kk][dd + 1];
      a[2] += p * Vs[kk][dd + 2];
      a[3] += p * Vs[kk][dd + 3];
    }
  }
  int row = b * SEQ + s0 + r;
  size_t base = (size_t)row * 2304;
#pragma unroll
  for (int j = 0; j < 4; j++) {
    int col = h * 64 + dd + j;
    u16 s; us8 u;
    expand9(a[j], &s, &u);
    Xe[base + col] = s;
    *(us8*)(Xe + base + 256 + (size_t)col * 8) = u;
  }
}

// ---------- launch ----------

extern "C" void kernel_launch(void* const* d_in, const int* in_sizes, int n_in,
                              void* d_out, int out_size, void* d_ws, size_t ws_size,
                              hipStream_t stream) {
  const int* ids = (const int*)d_in[0];
  const float* wemb = (const float*)d_in[1];
  const float* ttemb = (const float*)d_in[2];
  const float* pemb = (const float*)d_in[3];
  const float* elg = (const float*)d_in[4];
  const float* elb = (const float*)d_in[5];
  const float* qb = (const float*)d_in[6], *qs = (const float*)d_in[7];
  const float* kb = (const float*)d_in[8], *ks = (const float*)d_in[9];
  const float* vb = (const float*)d_in[10], *vs = (const float*)d_in[11];
  const float* ob = (const float*)d_in[12], *osp = (const float*)d_in[13];
  const float* f1b = (const float*)d_in[14], *f1s = (const float*)d_in[15];
  const float* f2b = (const float*)d_in[16], *f2s = (const float*)d_in[17];
  const float* l1g = (const float*)d_in[18], *l1b = (const float*)d_in[19];
  const float* l2g = (const float*)d_in[20], *l2b = (const float*)d_in[21];
  const float* hkb = (const float*)d_in[22], *hks = (const float*)d_in[23];
  const float* hob = (const float*)d_in[24], *hos = (const float*)d_in[25];
  float* out = (float*)d_out;

  char* w = (char*)d_ws;
  const size_t MB = 1 << 20;
  float* xbuf = (float*)(w);                 // 1 MB  [1024*256]
  float* tmp  = (float*)(w + 1 * MB);        // 1 MB  (head LN scratch)
  float* qkv  = (float*)(w + 2 * MB);        // 3 MB  [1024*768]
  float* part = (float*)(w + 5 * MB);        // 4 MB  [4][1024*256] split-K partials
  u16*   Xe2  = (u16*)  (w + 10 * MB);       // 18 MB [1024*9216]   f1-out expansion
  u16*   Xe   = (u16*)  (w + 28 * MB);       // 4.5MB [1024*2304]
  u16*   Wc   = (u16*)  (w + 33 * MB);       // 196 MB packed bf16 weights

  const size_t oq = 0, okk = 2359296, ov = 4718592, oo = 7077888;
  const size_t of1 = 9437184, of2 = 18874368, ohk = 28311552, oho = 28901376;

  {
    PackA pa;
    pa.b[0] = qb;  pa.s[0] = qs;  pa.off[0] = oq;  pa.shift[0] = 8;
    pa.b[1] = kb;  pa.s[1] = ks;  pa.off[1] = okk; pa.shift[1] = 8;
    pa.b[2] = vb;  pa.s[2] = vs;  pa.off[2] = ov;  pa.shift[2] = 8;
    pa.b[3] = ob;  pa.s[3] = osp; pa.off[3] = oo;  pa.shift[3] = 8;
    pa.b[4] = f1b; pa.s[4] = f1s; pa.off[4] = of1; pa.shift[4] = 8;
    pa.b[5] = f2b; pa.s[5] = f2s; pa.off[5] = of2; pa.shift[5] = 10;
    pa.b[6] = hkb; pa.s[6] = hks; pa.off[6] = ohk; pa.shift[6] = 8;
    pa.b[7] = hob; pa.s[7] = hos; pa.off[7] = oho; pa.shift[7] = 8;
    long long cum = 0;
    long long sz[8] = {262144, 262144, 262144, 262144, 1048576, 1048576, 65536, 8192000};
    for (int i = 0; i < 8; i++) { pa.cum[i] = cum; cum += sz[i]; }
    pa.cum[8] = cum;                          // 11,403,264 elems
    pack_all<<<(unsigned)((cum + 255) / 256), 256, 0, stream>>>(pa, Wc);
  }

  embed_ln_x<<<TOKENS, 256, 0, stream>>>(ids, wemb, ttemb, pemb, elg, elb, xbuf, Xe);

  for (int l = 0; l < 4; l++) {
    const size_t wl = (size_t)l * 589824, fl = (size_t)l * 2359296;

    gemm_b16<64, 64, 0, 2><<<dim3(16, 12), 256, 0, stream>>>(
        Xe, Wc + oq + wl, Wc + okk + wl, Wc + ov + wl, 256, 768, 2304, 2304,
        qkv, nullptr, 0);
    attn_fused<<<dim3(8, 32), 256, 0, stream>>>(qkv, Xe);
    gemm_b16<64, 64, 0, 2><<<dim3(16, 4, 2), 256, 0, stream>>>(
        Xe, Wc + oo + wl, Wc + oo + wl, Wc + oo + wl, 256, 256, 2304, 1152,
        part, nullptr, 0);
    add_ln_x<<<TOKENS, 256, 0, stream>>>(part, 2, TOKENS * 256, xbuf,
                                         l1g + l * 256, l1b + l * 256, 1e-5f, 0, xbuf, Xe);
    gemm_b16<64, 64, 1, 2><<<dim3(16, 16), 256, 0, stream>>>(
        Xe, Wc + of1 + fl, Wc + of1 + fl, Wc + of1 + fl, 1024, 1024, 2304, 2304,
        nullptr, Xe2, 1024);
    gemm_b16<64, 64, 0, 2><<<dim3(16, 4, 4), 256, 0, stream>>>(
        Xe2, Wc + of2 + fl, Wc + of2 + fl, Wc + of2 + fl, 256, 256, 9216, 2304,
        part, nullptr, 0);
    add_ln_x<<<TOKENS, 256, 0, stream>>>(part, 4, TOKENS * 256, xbuf,
                                         l2g + l * 256, l2b + l * 256, 1e-5f, 0, xbuf, Xe);
  }

  // head: KAN -> gelu -> LN(no affine, eps 1e-12) -> KAN to vocab
  gemm_b16<64, 64, 0, 2><<<dim3(16, 4, 2), 256, 0, stream>>>(
      Xe, Wc + ohk, Wc + ohk, Wc + ohk, 256, 256, 2304, 1152, part, nullptr, 0);
  add_ln_x<<<TOKENS, 256, 0, stream>>>(part, 2, TOKENS * 256, nullptr, nullptr, nullptr,
                                       1e-12f, 1, tmp, Xe);
  gemm_b16<128, 128, 0, 1><<<dim3(8, 250), 256, 0, stream>>>(
      Xe, Wc + oho, Wc + oho, Wc + oho, 32000, 32000, 2304, 2304, out, nullptr, 0);
}

// Round 5
// 1996.020 us; speedup vs baseline: 1.5159x; 1.5159x over previous
//
#include <hip/hip_runtime.h>
#include <math.h>

typedef unsigned short u16;
typedef unsigned int u32;
typedef __bf16 bf16x8 __attribute__((ext_vector_type(8)));
typedef float f32x4 __attribute__((ext_vector_type(4)));
typedef u16 us8 __attribute__((ext_vector_type(8)));

#define TOKENS 1024
#define DIM 256
#define SEQ 512

// ---------- helpers ----------

__device__ __forceinline__ u16 f2bf(float f) {
  u32 x = __float_as_uint(f);
  x += 0x7fffu + ((x >> 16) & 1u);
  return (u16)(x >> 16);
}

// silu + 8 cubic B-spline bases (uniform extended grid g[j] = (j-3)*0.4f - 1.0f)
__device__ __forceinline__ void expand9(float x, u16* sil, us8* u) {
  float sig = 1.0f / (1.0f + expf(-x));
  *sil = f2bf(x * sig);
  float bs[11];
#pragma unroll
  for (int j = 0; j < 11; j++) {
    float gj  = (float)(j - 3) * 0.4f - 1.0f;
    float gj1 = (float)(j - 2) * 0.4f - 1.0f;
    bs[j] = (x >= gj && x < gj1) ? 1.0f : 0.0f;
  }
#pragma unroll
  for (int k = 1; k <= 3; k++) {
#pragma unroll
    for (int j = 0; j < 10; j++) {
      if (j + k < 11) {
        float gj   = (float)(j - 3) * 0.4f - 1.0f;
        float gj1  = (float)(j - 2) * 0.4f - 1.0f;
        float gjk  = (float)(j + k - 3) * 0.4f - 1.0f;
        float gjk1 = (float)(j + k - 2) * 0.4f - 1.0f;
        bs[j] = (x - gj) / (gjk - gj) * bs[j] + (gjk1 - x) / (gjk1 - gj1) * bs[j + 1];
      }
    }
  }
#pragma unroll
  for (int c = 0; c < 8; c++) (*u)[c] = f2bf(bs[c]);
}

// 256-thread block sum (4 waves of 64)
__device__ __forceinline__ float block_sum_256(float v) {
  __shared__ float red[4];
  int t = threadIdx.x, lane = t & 63, wid = t >> 6;
#pragma unroll
  for (int o = 32; o > 0; o >>= 1) v += __shfl_down(v, o, 64);
  __syncthreads();
  if (lane == 0) red[wid] = v;
  __syncthreads();
  return red[0] + red[1] + red[2] + red[3];
}

// ---------- embedding + LN (eps 1e-12) + expand ----------

__global__ void embed_ln_x(const int* __restrict__ ids, const float* __restrict__ wemb,
                           const float* __restrict__ tt, const float* __restrict__ pe,
                           const float* __restrict__ g, const float* __restrict__ bta,
                           float* __restrict__ xout, u16* __restrict__ Xe) {
  int row = blockIdx.x, t = threadIdx.x;
  int id = ids[row];
  float v = wemb[(size_t)id * DIM + t] + tt[DIM + t] + pe[DIM + t];
  float mu = block_sum_256(v) * (1.0f / 256.0f);
  float d = v - mu;
  float var = block_sum_256(d * d) * (1.0f / 256.0f);
  float y = d * rsqrtf(var + 1e-12f) * g[t] + bta[t];
  xout[(size_t)row * DIM + t] = y;
  size_t base = (size_t)row * 2304;
  u16 s; us8 u;
  expand9(y, &s, &u);
  Xe[base + t] = s;
  *(us8*)(Xe + base + 256 + (size_t)t * 8) = u;
}

// ---------- (sum of nsum partials) [+gelu] [+res] + LN + expand ----------

__global__ void add_ln_x(const float* __restrict__ a, int nsum, int sstride,
                         const float* __restrict__ res,
                         const float* __restrict__ g, const float* __restrict__ bta,
                         float eps, int dogelu,
                         float* __restrict__ xout, u16* __restrict__ Xe) {
  int row = blockIdx.x, t = threadIdx.x;
  int idx = row * 256 + t;
  float v = 0.f;
  for (int s = 0; s < nsum; s++) v += a[(size_t)s * sstride + idx];
  if (dogelu) v = 0.5f * v * (1.0f + erff(v * 0.70710678118654752f));
  if (res) v += res[idx];
  float mu = block_sum_256(v) * (1.0f / 256.0f);
  float d = v - mu;
  float var = block_sum_256(d * d) * (1.0f / 256.0f);
  float y = d * rsqrtf(var + eps);
  if (g) y = y * g[t] + bta[t];
  xout[idx] = y;
  size_t base = (size_t)row * 2304;
  u16 s16; us8 u;
  expand9(y, &s16, &u);
  Xe[base + t] = s16;
  *(us8*)(Xe + base + 256 + (size_t)t * 8) = u;
}

// ---------- all-weight pack in one dispatch ----------

struct PackA {
  const float* b[8];
  const float* s[8];
  unsigned long long off[8];   // elem offset into Wc
  long long cum[9];            // cumulative element counts
  int shift[8];
};

__global__ void pack_all(PackA pa, u16* __restrict__ Wc) {
  long idx = (long)blockIdx.x * 256 + threadIdx.x;
  if (idx >= pa.cum[8]) return;
  int s = 0;
#pragma unroll
  for (int i = 1; i < 8; i++) if (idx >= pa.cum[i]) s = i;
  long local = idx - pa.cum[s];
  int shift = pa.shift[s];
  int infeat = 1 << shift;
  long r = local >> shift;
  int i = (int)(local & (infeat - 1));
  int K = infeat * 9;
  u16* dst = Wc + pa.off[s];
  dst[(size_t)r * K + i] = f2bf(pa.b[s][local]);
  const float* sp = pa.s[s] + (size_t)local * 8;
  float4 f0 = *(const float4*)sp;
  float4 f1v = *(const float4*)(sp + 4);
  us8 u;
  u[0] = f2bf(f0.x); u[1] = f2bf(f0.y); u[2] = f2bf(f0.z); u[3] = f2bf(f0.w);
  u[4] = f2bf(f1v.x); u[5] = f2bf(f1v.y); u[6] = f2bf(f1v.z); u[7] = f2bf(f1v.w);
  *(us8*)(dst + (size_t)r * K + infeat + (size_t)i * 8) = u;
}

// ---------- GEMM (packed bf16 weights): C[1024,N] = A[1024,K] @ W[N,K]^T ----------
// XCD-contiguous remap, XOR-swizzled LDS, register prefetch in NAMED registers
// (no arrays, no lambdas -> nothing can be demoted to scratch).
// blockIdx.z = K-split slice (kchunk each); partial C at z*TOKENS*N.
// EPI: 0 = f32 store; 1 = relu + KAN-expand into XeOut (ld = infOut*9).

// staging: chunk c covers rows [c*32, c*32+32); thread t handles row c*32+(t>>3),
// 16B group ch = t&7; LDS slot XOR-swizzled: row*BK + ((ch ^ (row&7))*8).
#define LD_A(c, v) { int rr_ = (c) * 32 + (t >> 3); int ch_ = t & 7; \
    v = *(const uint4*)(A + (size_t)(m0 + rr_) * K + k0n + ch_ * 8); }
#define LD_B(c, v) { int rr_ = (c) * 32 + (t >> 3); int ch_ = t & 7; \
    v = *(const uint4*)(W + (size_t)(onb + rr_) * K + k0n + ch_ * 8); }
#define ST_A(c, v) { int rr_ = (c) * 32 + (t >> 3); int ch_ = t & 7; \
    *(uint4*)(&As[rr_ * BK + ((ch_ ^ (rr_ & 7)) << 3)]) = v; }
#define ST_B(c, v) { int rr_ = (c) * 32 + (t >> 3); int ch_ = t & 7; \
    *(uint4*)(&Bs[rr_ * BK + ((ch_ ^ (rr_ & 7)) << 3)]) = v; }

template <int BM, int BN, int EPI, int MINW>
__global__ __launch_bounds__(256, MINW)
void gemm_b16(const u16* __restrict__ A,
              const u16* __restrict__ W0, const u16* __restrict__ W1, const u16* __restrict__ W2,
              int nper, int N, int K, int kchunk,
              float* __restrict__ C, u16* __restrict__ XeOut, int infOut) {
  constexpr int BK = 64;
  constexpr int FM = BM / 32, FN = BN / 32;
  constexpr int NA = BM / 32, NB = BN / 32;     // 16B-staging chunks (2 or 4)
  static_assert(NA == 2 || NA == 4, "BM must be 64 or 128");
  static_assert(NB == 2 || NB == 4, "BN must be 64 or 128");
  __shared__ u16 As[BM * BK];
  __shared__ u16 Bs[BN * BK];
  const int gx = gridDim.x;
  const int nwg = gx * gridDim.y;
  int g = blockIdx.y * gx + blockIdx.x;
  int lin = g;
  if ((nwg & 7) == 0) lin = (g & 7) * (nwg >> 3) + (g >> 3);
  const int m0 = (lin % gx) * BM;
  const int n0 = (lin / gx) * BN;
  const int z = blockIdx.z;
  const int kbeg = z * kchunk;
  const int kend = (kbeg + kchunk < K) ? kbeg + kchunk : K;
  const int t = threadIdx.x;
  const int lane = t & 63, wid = t >> 6;
  const int wm = (wid >> 1) * (BM / 2), wn = (wid & 1) * (BN / 2);
  const int proj = n0 / nper;
  const u16* W = proj == 0 ? W0 : (proj == 1 ? W1 : W2);
  const int onb = n0 - proj * nper;

  f32x4 acc[FM][FN];
#pragma unroll
  for (int i = 0; i < FM; i++)
#pragma unroll
    for (int j = 0; j < FN; j++) acc[i][j] = (f32x4){0.f, 0.f, 0.f, 0.f};

  const int frow = lane & 15;
  const int cgrp = lane >> 4;

  uint4 pa0, pa1, pa2, pa3, pb0, pb1, pb2, pb3;
  int k0n = kbeg;
  LD_A(0, pa0); LD_A(1, pa1);
  if constexpr (NA == 4) { LD_A(2, pa2); LD_A(3, pa3); }
  LD_B(0, pb0); LD_B(1, pb1);
  if constexpr (NB == 4) { LD_B(2, pb2); LD_B(3, pb3); }

  for (int k0 = kbeg; k0 < kend; k0 += BK) {
    ST_A(0, pa0); ST_A(1, pa1);
    if constexpr (NA == 4) { ST_A(2, pa2); ST_A(3, pa3); }
    ST_B(0, pb0); ST_B(1, pb1);
    if constexpr (NB == 4) { ST_B(2, pb2); ST_B(3, pb3); }
    __syncthreads();
    if (k0 + BK < kend) {                     // prefetch next tile into registers
      k0n = k0 + BK;
      LD_A(0, pa0); LD_A(1, pa1);
      if constexpr (NA == 4) { LD_A(2, pa2); LD_A(3, pa3); }
      LD_B(0, pb0); LD_B(1, pb1);
      if constexpr (NB == 4) { LD_B(2, pb2); LD_B(3, pb3); }
    }
#pragma unroll
    for (int half = 0; half < 2; half++) {
      const int ch = half * 4 + cgrp;
      bf16x8 af[FM], bfr[FN];
#pragma unroll
      for (int i = 0; i < FM; i++) {
        int rr = wm + i * 16 + frow;
        af[i] = *reinterpret_cast<const bf16x8*>(&As[rr * BK + ((ch ^ (rr & 7)) << 3)]);
      }
#pragma unroll
      for (int j = 0; j < FN; j++) {
        int rr = wn + j * 16 + frow;
        bfr[j] = *reinterpret_cast<const bf16x8*>(&Bs[rr * BK + ((ch ^ (rr & 7)) << 3)]);
      }
#pragma unroll
      for (int i = 0; i < FM; i++)
#pragma unroll
        for (int j = 0; j < FN; j++)
          acc[i][j] = __builtin_amdgcn_mfma_f32_16x16x32_bf16(af[i], bfr[j], acc[i][j], 0, 0, 0);
    }
    __syncthreads();
  }

  const int crow = (lane >> 4) * 4;
  const int ccol = lane & 15;
  if (EPI == 0) {
    float* Cz = C + (size_t)z * TOKENS * N;
#pragma unroll
    for (int i = 0; i < FM; i++)
#pragma unroll
      for (int j = 0; j < FN; j++) {
        int row = m0 + wm + i * 16 + crow;
        int col = n0 + wn + j * 16 + ccol;
#pragma unroll
        for (int r = 0; r < 4; r++)
          Cz[(size_t)(row + r) * N + col] = acc[i][j][r];
      }
  } else {
    const int ldXe = infOut * 9;
#pragma unroll
    for (int i = 0; i < FM; i++)
#pragma unroll
      for (int j = 0; j < FN; j++) {
        int row0 = m0 + wm + i * 16 + crow;
        int col = n0 + wn + j * 16 + ccol;
#pragma unroll
        for (int r = 0; r < 4; r++) {
          float y = fmaxf(acc[i][j][r], 0.0f);     // relu
          u16 s; us8 u;
          expand9(y, &s, &u);
          size_t base = (size_t)(row0 + r) * ldXe;
          XeOut[base + col] = s;
          *(us8*)(XeOut + base + infOut + (size_t)col * 8) = u;
        }
      }
  }
}

// ---------- fused attention: QK^T + softmax + PV + KAN-expand (P stays in LDS) ----------

__global__ void attn_fused(const float* __restrict__ qkv, u16* __restrict__ Xe) {
  int bh = blockIdx.x, b = bh >> 2, h = bh & 3;
  int s0 = blockIdx.y * 16;
  int t = threadIdx.x;
  __shared__ float Qs[16][64];
  __shared__ float Ks[16][65];
  __shared__ float Ss[16][513];
  __shared__ float red[16][17];
  __shared__ float Vs[32][65];
#pragma unroll
  for (int c = 0; c < 4; c++) {
    int e = c * 256 + t, r = e >> 6, d = e & 63;
    Qs[r][d] = qkv[(size_t)(b * SEQ + s0 + r) * 768 + h * 64 + d];
  }
  int r = t >> 4, cc = t & 15;
  for (int kc = 0; kc < SEQ; kc += 16) {
    __syncthreads();
#pragma unroll
    for (int c = 0; c < 4; c++) {
      int e = c * 256 + t, rr = e >> 6, d = e & 63;
      Ks[rr][d] = qkv[(size_t)(b * SEQ + kc + rr) * 768 + 256 + h * 64 + d];
    }
    __syncthreads();
    float acc = 0.f;
#pragma unroll
    for (int d = 0; d < 64; d++) acc += Qs[r][d] * Ks[cc][d];
    Ss[r][kc + cc] = acc * 0.125f;
  }
  __syncthreads();
  float mx = -3.4e38f;
  for (int j = cc; j < SEQ; j += 16) mx = fmaxf(mx, Ss[r][j]);
  red[r][cc] = mx;
  __syncthreads();
  if (cc == 0) {
    float m = red[r][0];
#pragma unroll
    for (int j = 1; j < 16; j++) m = fmaxf(m, red[r][j]);
    red[r][16] = m;
  }
  __syncthreads();
  mx = red[r][16];
  float sm = 0.f;
  for (int j = cc; j < SEQ; j += 16) {
    float e = expf(Ss[r][j] - mx);
    Ss[r][j] = e;
    sm += e;
  }
  __syncthreads();
  red[r][cc] = sm;
  __syncthreads();
  if (cc == 0) {
    float s = 0.f;
#pragma unroll
    for (int j = 0; j < 16; j++) s += red[r][j];
    red[r][16] = s;
  }
  __syncthreads();
  float inv = 1.0f / red[r][16];
  for (int j = cc; j < SEQ; j += 16) Ss[r][j] *= inv;
  // PV
  int dd = cc * 4;
  float a0 = 0.f, a1 = 0.f, a2 = 0.f, a3 = 0.f;
  for (int kc = 0; kc < SEQ; kc += 32) {
    __syncthreads();
#pragma unroll
    for (int c = 0; c < 8; c++) {
      int e = c * 256 + t, rr = e >> 6, d = e & 63;
      Vs[rr][d] = qkv[(size_t)(b * SEQ + kc + rr) * 768 + 512 + h * 64 + d];
    }
    __syncthreads();
#pragma unroll
    for (int kk = 0; kk < 32; kk++) {
      float p = Ss[r][kc + kk];
      a0 += p * Vs[kk][dd + 0];
      a1 += p * Vs[kk][dd + 1];
      a2 += p * Vs[kk][dd + 2];
      a3 += p * Vs[kk][dd + 3];
    }
  }
  int row = b * SEQ + s0 + r;
  size_t base = (size_t)row * 2304;
  float av[4] = {a0, a1, a2, a3};
#pragma unroll
  for (int j = 0; j < 4; j++) {
    int col = h * 64 + dd + j;
    u16 s; us8 u;
    expand9(av[j], &s, &u);
    Xe[base + col] = s;
    *(us8*)(Xe + base + 256 + (size_t)col * 8) = u;
  }
}

// ---------- launch ----------

extern "C" void kernel_launch(void* const* d_in, const int* in_sizes, int n_in,
                              void* d_out, int out_size, void* d_ws, size_t ws_size,
                              hipStream_t stream) {
  const int* ids = (const int*)d_in[0];
  const float* wemb = (const float*)d_in[1];
  const float* ttemb = (const float*)d_in[2];
  const float* pemb = (const float*)d_in[3];
  const float* elg = (const float*)d_in[4];
  const float* elb = (const float*)d_in[5];
  const float* qb = (const float*)d_in[6], *qs = (const float*)d_in[7];
  const float* kb = (const float*)d_in[8], *ks = (const float*)d_in[9];
  const float* vb = (const float*)d_in[10], *vs = (const float*)d_in[11];
  const float* ob = (const float*)d_in[12], *osp = (const float*)d_in[13];
  const float* f1b = (const float*)d_in[14], *f1s = (const float*)d_in[15];
  const float* f2b = (const float*)d_in[16], *f2s = (const float*)d_in[17];
  const float* l1g = (const float*)d_in[18], *l1b = (const float*)d_in[19];
  const float* l2g = (const float*)d_in[20], *l2b = (const float*)d_in[21];
  const float* hkb = (const float*)d_in[22], *hks = (const float*)d_in[23];
  const float* hob = (const float*)d_in[24], *hos = (const float*)d_in[25];
  float* out = (float*)d_out;

  char* w = (char*)d_ws;
  const size_t MB = 1 << 20;
  float* xbuf = (float*)(w);                 // 1 MB  [1024*256]
  float* tmp  = (float*)(w + 1 * MB);        // 1 MB  (head LN scratch)
  float* qkv  = (float*)(w + 2 * MB);        // 3 MB  [1024*768]
  float* part = (float*)(w + 5 * MB);        // 4 MB  [4][1024*256] split-K partials
  u16*   Xe2  = (u16*)  (w + 10 * MB);       // 18 MB [1024*9216]   f1-out expansion
  u16*   Xe   = (u16*)  (w + 28 * MB);       // 4.5MB [1024*2304]
  u16*   Wc   = (u16*)  (w + 33 * MB);       // 196 MB packed bf16 weights

  const size_t oq = 0, okk = 2359296, ov = 4718592, oo = 7077888;
  const size_t of1 = 9437184, of2 = 18874368, ohk = 28311552, oho = 28901376;

  {
    PackA pa;
    pa.b[0] = qb;  pa.s[0] = qs;  pa.off[0] = oq;  pa.shift[0] = 8;
    pa.b[1] = kb;  pa.s[1] = ks;  pa.off[1] = okk; pa.shift[1] = 8;
    pa.b[2] = vb;  pa.s[2] = vs;  pa.off[2] = ov;  pa.shift[2] = 8;
    pa.b[3] = ob;  pa.s[3] = osp; pa.off[3] = oo;  pa.shift[3] = 8;
    pa.b[4] = f1b; pa.s[4] = f1s; pa.off[4] = of1; pa.shift[4] = 8;
    pa.b[5] = f2b; pa.s[5] = f2s; pa.off[5] = of2; pa.shift[5] = 10;
    pa.b[6] = hkb; pa.s[6] = hks; pa.off[6] = ohk; pa.shift[6] = 8;
    pa.b[7] = hob; pa.s[7] = hos; pa.off[7] = oho; pa.shift[7] = 8;
    long long cum = 0;
    long long sz[8] = {262144, 262144, 262144, 262144, 1048576, 1048576, 65536, 8192000};
    for (int i = 0; i < 8; i++) { pa.cum[i] = cum; cum += sz[i]; }
    pa.cum[8] = cum;                          // 11,403,264 elems
    pack_all<<<(unsigned)((cum + 255) / 256), 256, 0, stream>>>(pa, Wc);
  }

  embed_ln_x<<<TOKENS, 256, 0, stream>>>(ids, wemb, ttemb, pemb, elg, elb, xbuf, Xe);

  for (int l = 0; l < 4; l++) {
    const size_t wl = (size_t)l * 589824, fl = (size_t)l * 2359296;

    gemm_b16<64, 64, 0, 2><<<dim3(16, 12), 256, 0, stream>>>(
        Xe, Wc + oq + wl, Wc + okk + wl, Wc + ov + wl, 256, 768, 2304, 2304,
        qkv, nullptr, 0);
    attn_fused<<<dim3(8, 32), 256, 0, stream>>>(qkv, Xe);
    gemm_b16<64, 64, 0, 2><<<dim3(16, 4, 2), 256, 0, stream>>>(
        Xe, Wc + oo + wl, Wc + oo + wl, Wc + oo + wl, 256, 256, 2304, 1152,
        part, nullptr, 0);
    add_ln_x<<<TOKENS, 256, 0, stream>>>(part, 2, TOKENS * 256, xbuf,
                                         l1g + l * 256, l1b + l * 256, 1e-5f, 0, xbuf, Xe);
    gemm_b16<64, 64, 1, 2><<<dim3(16, 16), 256, 0, stream>>>(
        Xe, Wc + of1 + fl, Wc + of1 + fl, Wc + of1 + fl, 1024, 1024, 2304, 2304,
        nullptr, Xe2, 1024);
    gemm_b16<64, 64, 0, 2><<<dim3(16, 4, 4), 256, 0, stream>>>(
        Xe2, Wc + of2 + fl, Wc + of2 + fl, Wc + of2 + fl, 256, 256, 9216, 2304,
        part, nullptr, 0);
    add_ln_x<<<TOKENS, 256, 0, stream>>>(part, 4, TOKENS * 256, xbuf,
                                         l2g + l * 256, l2b + l * 256, 1e-5f, 0, xbuf, Xe);
  }

  // head: KAN -> gelu -> LN(no affine, eps 1e-12) -> KAN to vocab
  gemm_b16<64, 64, 0, 2><<<dim3(16, 4, 2), 256, 0, stream>>>(
      Xe, Wc + ohk, Wc + ohk, Wc + ohk, 256, 256, 2304, 1152, part, nullptr, 0);
  add_ln_x<<<TOKENS, 256, 0, stream>>>(part, 2, TOKENS * 256, nullptr, nullptr, nullptr,
                                       1e-12f, 1, tmp, Xe);
  gemm_b16<128, 128, 0, 1><<<dim3(8, 250), 256, 0, stream>>>(
      Xe, Wc + oho, Wc + oho, Wc + oho, 32000, 32000, 2304, 2304, out, nullptr, 0);
}

// Round 6
// 1199.386 us; speedup vs baseline: 2.5228x; 1.6642x over previous
//
#include <hip/hip_runtime.h>
#include <math.h>

typedef unsigned short u16;
typedef unsigned int u32;
typedef __bf16 bf16x8 __attribute__((ext_vector_type(8)));
typedef float f32x4 __attribute__((ext_vector_type(4)));
typedef u16 us8 __attribute__((ext_vector_type(8)));

#define TOKENS 1024
#define DIM 256
#define SEQ 512

// ---------- helpers ----------

__device__ __forceinline__ u16 f2bf(float f) {
  u32 x = __float_as_uint(f);
  x += 0x7fffu + ((x >> 16) & 1u);
  return (u16)(x >> 16);
}

// silu + 8 cubic B-spline bases, uniform extended grid g[j] = (j-3)*0.4f - 1.0f.
// Divisions replaced by compile-time reciprocals (denominators are constants;
// folds at -O3 since j,k are unroll constants). <=1ulp deviation per basis.
__device__ __forceinline__ void expand9(float x, u16* sil, us8* u) {
  float sig = 1.0f / (1.0f + expf(-x));
  *sil = f2bf(x * sig);
  float bs[11];
#pragma unroll
  for (int j = 0; j < 11; j++) {
    float gj  = (float)(j - 3) * 0.4f - 1.0f;
    float gj1 = (float)(j - 2) * 0.4f - 1.0f;
    bs[j] = (x >= gj && x < gj1) ? 1.0f : 0.0f;
  }
#pragma unroll
  for (int k = 1; k <= 3; k++) {
#pragma unroll
    for (int j = 0; j < 10; j++) {
      if (j + k < 11) {
        float gj   = (float)(j - 3) * 0.4f - 1.0f;
        float gj1  = (float)(j - 2) * 0.4f - 1.0f;
        float gjk  = (float)(j + k - 3) * 0.4f - 1.0f;
        float gjk1 = (float)(j + k - 2) * 0.4f - 1.0f;
        float linv = 1.0f / (gjk - gj);      // compile-time constant
        float rinv = 1.0f / (gjk1 - gj1);    // compile-time constant
        bs[j] = (x - gj) * linv * bs[j] + (gjk1 - x) * rinv * bs[j + 1];
      }
    }
  }
#pragma unroll
  for (int c = 0; c < 8; c++) (*u)[c] = f2bf(bs[c]);
}

// 256-thread block sum (4 waves of 64)
__device__ __forceinline__ float block_sum_256(float v) {
  __shared__ float red[4];
  int t = threadIdx.x, lane = t & 63, wid = t >> 6;
#pragma unroll
  for (int o = 32; o > 0; o >>= 1) v += __shfl_down(v, o, 64);
  __syncthreads();
  if (lane == 0) red[wid] = v;
  __syncthreads();
  return red[0] + red[1] + red[2] + red[3];
}

// ---------- embedding + LN (eps 1e-12) + expand ----------

__global__ void embed_ln_x(const int* __restrict__ ids, const float* __restrict__ wemb,
                           const float* __restrict__ tt, const float* __restrict__ pe,
                           const float* __restrict__ g, const float* __restrict__ bta,
                           float* __restrict__ xout, u16* __restrict__ Xe) {
  int row = blockIdx.x, t = threadIdx.x;
  int id = ids[row];
  float v = wemb[(size_t)id * DIM + t] + tt[DIM + t] + pe[DIM + t];
  float mu = block_sum_256(v) * (1.0f / 256.0f);
  float d = v - mu;
  float var = block_sum_256(d * d) * (1.0f / 256.0f);
  float y = d * rsqrtf(var + 1e-12f) * g[t] + bta[t];
  xout[(size_t)row * DIM + t] = y;
  size_t base = (size_t)row * 2304;
  u16 s; us8 u;
  expand9(y, &s, &u);
  Xe[base + t] = s;
  *(us8*)(Xe + base + 256 + (size_t)t * 8) = u;
}

// ---------- (sum of nsum partials) [+gelu] [+res] + LN + expand ----------

__global__ void add_ln_x(const float* __restrict__ a, int nsum, int sstride,
                         const float* __restrict__ res,
                         const float* __restrict__ g, const float* __restrict__ bta,
                         float eps, int dogelu,
                         float* __restrict__ xout, u16* __restrict__ Xe) {
  int row = blockIdx.x, t = threadIdx.x;
  int idx = row * 256 + t;
  float v = 0.f;
  for (int s = 0; s < nsum; s++) v += a[(size_t)s * sstride + idx];
  if (dogelu) v = 0.5f * v * (1.0f + erff(v * 0.70710678118654752f));
  if (res) v += res[idx];
  float mu = block_sum_256(v) * (1.0f / 256.0f);
  float d = v - mu;
  float var = block_sum_256(d * d) * (1.0f / 256.0f);
  float y = d * rsqrtf(var + eps);
  if (g) y = y * g[t] + bta[t];
  xout[idx] = y;
  size_t base = (size_t)row * 2304;
  u16 s16; us8 u;
  expand9(y, &s16, &u);
  Xe[base + t] = s16;
  *(us8*)(Xe + base + 256 + (size_t)t * 8) = u;
}

// ---------- relu + expand for FF hidden: ff1[1024,1024] f32 -> Xe2[1024, 9216] bf16 ----------

__global__ void expand_ff(const float* __restrict__ X, u16* __restrict__ Xe) {
  int idx = blockIdx.x * 256 + threadIdx.x;
  int n = idx >> 10, i = idx & 1023;
  float x = fmaxf(X[idx], 0.0f);
  u16 s; us8 u;
  expand9(x, &s, &u);
  size_t base = (size_t)n * 9216;
  Xe[base + i] = s;
  *(us8*)(Xe + base + 1024 + (size_t)i * 8) = u;
}

// ---------- all-weight pack in one dispatch ----------

struct PackA {
  const float* b[8];
  const float* s[8];
  unsigned long long off[8];   // elem offset into Wc
  long long cum[9];            // cumulative element counts
  int shift[8];
};

__global__ void pack_all(PackA pa, u16* __restrict__ Wc) {
  long idx = (long)blockIdx.x * 256 + threadIdx.x;
  if (idx >= pa.cum[8]) return;
  int s = 0;
#pragma unroll
  for (int i = 1; i < 8; i++) if (idx >= pa.cum[i]) s = i;
  long local = idx - pa.cum[s];
  int shift = pa.shift[s];
  int infeat = 1 << shift;
  long r = local >> shift;
  int i = (int)(local & (infeat - 1));
  int K = infeat * 9;
  u16* dst = Wc + pa.off[s];
  dst[(size_t)r * K + i] = f2bf(pa.b[s][local]);
  const float* sp = pa.s[s] + (size_t)local * 8;
  float4 f0 = *(const float4*)sp;
  float4 f1v = *(const float4*)(sp + 4);
  us8 u;
  u[0] = f2bf(f0.x); u[1] = f2bf(f0.y); u[2] = f2bf(f0.z); u[3] = f2bf(f0.w);
  u[4] = f2bf(f1v.x); u[5] = f2bf(f1v.y); u[6] = f2bf(f1v.z); u[7] = f2bf(f1v.w);
  *(us8*)(dst + (size_t)r * K + infeat + (size_t)i * 8) = u;
}

// ---------- GEMM (packed bf16 weights): C[1024,N] = A[1024,K] @ W[N,K]^T ----------
// XCD-contiguous remap, XOR-swizzled LDS, register prefetch in NAMED registers.
// blockIdx.z = K-split slice (kchunk each); partial C at z*TOKENS*N.

#define LD_A(c, v) { int rr_ = (c) * 32 + (t >> 3); int ch_ = t & 7; \
    v = *(const uint4*)(A + (size_t)(m0 + rr_) * K + k0n + ch_ * 8); }
#define LD_B(c, v) { int rr_ = (c) * 32 + (t >> 3); int ch_ = t & 7; \
    v = *(const uint4*)(W + (size_t)(onb + rr_) * K + k0n + ch_ * 8); }
#define ST_A(c, v) { int rr_ = (c) * 32 + (t >> 3); int ch_ = t & 7; \
    *(uint4*)(&As[rr_ * BK + ((ch_ ^ (rr_ & 7)) << 3)]) = v; }
#define ST_B(c, v) { int rr_ = (c) * 32 + (t >> 3); int ch_ = t & 7; \
    *(uint4*)(&Bs[rr_ * BK + ((ch_ ^ (rr_ & 7)) << 3)]) = v; }

template <int BM, int BN, int MINW>
__global__ __launch_bounds__(256, MINW)
void gemm_b16(const u16* __restrict__ A,
              const u16* __restrict__ W0, const u16* __restrict__ W1, const u16* __restrict__ W2,
              int nper, int N, int K, int kchunk, float* __restrict__ C) {
  constexpr int BK = 64;
  constexpr int FM = BM / 32, FN = BN / 32;
  constexpr int NA = BM / 32, NB = BN / 32;
  static_assert(NA == 2 || NA == 4, "BM must be 64 or 128");
  static_assert(NB == 2 || NB == 4, "BN must be 64 or 128");
  __shared__ u16 As[BM * BK];
  __shared__ u16 Bs[BN * BK];
  const int gx = gridDim.x;
  const int nwg = gx * gridDim.y;
  int g = blockIdx.y * gx + blockIdx.x;
  int lin = g;
  if ((nwg & 7) == 0) lin = (g & 7) * (nwg >> 3) + (g >> 3);
  const int m0 = (lin % gx) * BM;
  const int n0 = (lin / gx) * BN;
  const int z = blockIdx.z;
  const int kbeg = z * kchunk;
  const int kend = (kbeg + kchunk < K) ? kbeg + kchunk : K;
  const int t = threadIdx.x;
  const int lane = t & 63, wid = t >> 6;
  const int wm = (wid >> 1) * (BM / 2), wn = (wid & 1) * (BN / 2);
  const int proj = n0 / nper;
  const u16* W = proj == 0 ? W0 : (proj == 1 ? W1 : W2);
  const int onb = n0 - proj * nper;

  f32x4 acc[FM][FN];
#pragma unroll
  for (int i = 0; i < FM; i++)
#pragma unroll
    for (int j = 0; j < FN; j++) acc[i][j] = (f32x4){0.f, 0.f, 0.f, 0.f};

  const int frow = lane & 15;
  const int cgrp = lane >> 4;

  uint4 pa0, pa1, pa2, pa3, pb0, pb1, pb2, pb3;
  int k0n = kbeg;
  LD_A(0, pa0); LD_A(1, pa1);
  if constexpr (NA == 4) { LD_A(2, pa2); LD_A(3, pa3); }
  LD_B(0, pb0); LD_B(1, pb1);
  if constexpr (NB == 4) { LD_B(2, pb2); LD_B(3, pb3); }

  for (int k0 = kbeg; k0 < kend; k0 += BK) {
    ST_A(0, pa0); ST_A(1, pa1);
    if constexpr (NA == 4) { ST_A(2, pa2); ST_A(3, pa3); }
    ST_B(0, pb0); ST_B(1, pb1);
    if constexpr (NB == 4) { ST_B(2, pb2); ST_B(3, pb3); }
    __syncthreads();
    if (k0 + BK < kend) {                     // prefetch next tile into registers
      k0n = k0 + BK;
      LD_A(0, pa0); LD_A(1, pa1);
      if constexpr (NA == 4) { LD_A(2, pa2); LD_A(3, pa3); }
      LD_B(0, pb0); LD_B(1, pb1);
      if constexpr (NB == 4) { LD_B(2, pb2); LD_B(3, pb3); }
    }
#pragma unroll
    for (int half = 0; half < 2; half++) {
      const int ch = half * 4 + cgrp;
      bf16x8 af[FM], bfr[FN];
#pragma unroll
      for (int i = 0; i < FM; i++) {
        int rr = wm + i * 16 + frow;
        af[i] = *reinterpret_cast<const bf16x8*>(&As[rr * BK + ((ch ^ (rr & 7)) << 3)]);
      }
#pragma unroll
      for (int j = 0; j < FN; j++) {
        int rr = wn + j * 16 + frow;
        bfr[j] = *reinterpret_cast<const bf16x8*>(&Bs[rr * BK + ((ch ^ (rr & 7)) << 3)]);
      }
#pragma unroll
      for (int i = 0; i < FM; i++)
#pragma unroll
        for (int j = 0; j < FN; j++)
          acc[i][j] = __builtin_amdgcn_mfma_f32_16x16x32_bf16(af[i], bfr[j], acc[i][j], 0, 0, 0);
    }
    __syncthreads();
  }

  const int crow = (lane >> 4) * 4;
  const int ccol = lane & 15;
  float* Cz = C + (size_t)z * TOKENS * N;
#pragma unroll
  for (int i = 0; i < FM; i++)
#pragma unroll
    for (int j = 0; j < FN; j++) {
      int row = m0 + wm + i * 16 + crow;
      int col = n0 + wn + j * 16 + ccol;
#pragma unroll
      for (int r = 0; r < 4; r++)
        Cz[(size_t)(row + r) * N + col] = acc[i][j][r];
    }
}

// ---------- fused attention: QK^T + softmax + PV + KAN-expand (P stays in LDS) ----------

__global__ void attn_fused(const float* __restrict__ qkv, u16* __restrict__ Xe) {
  int bh = blockIdx.x, b = bh >> 2, h = bh & 3;
  int s0 = blockIdx.y * 16;
  int t = threadIdx.x;
  __shared__ float Qs[16][64];
  __shared__ float Ks[16][65];
  __shared__ float Ss[16][513];
  __shared__ float red[16][17];
  __shared__ float Vs[32][65];
#pragma unroll
  for (int c = 0; c < 4; c++) {
    int e = c * 256 + t, r = e >> 6, d = e & 63;
    Qs[r][d] = qkv[(size_t)(b * SEQ + s0 + r) * 768 + h * 64 + d];
  }
  int r = t >> 4, cc = t & 15;
  for (int kc = 0; kc < SEQ; kc += 16) {
    __syncthreads();
#pragma unroll
    for (int c = 0; c < 4; c++) {
      int e = c * 256 + t, rr = e >> 6, d = e & 63;
      Ks[rr][d] = qkv[(size_t)(b * SEQ + kc + rr) * 768 + 256 + h * 64 + d];
    }
    __syncthreads();
    float acc = 0.f;
#pragma unroll
    for (int d = 0; d < 64; d++) acc += Qs[r][d] * Ks[cc][d];
    Ss[r][kc + cc] = acc * 0.125f;
  }
  __syncthreads();
  float mx = -3.4e38f;
  for (int j = cc; j < SEQ; j += 16) mx = fmaxf(mx, Ss[r][j]);
  red[r][cc] = mx;
  __syncthreads();
  if (cc == 0) {
    float m = red[r][0];
#pragma unroll
    for (int j = 1; j < 16; j++) m = fmaxf(m, red[r][j]);
    red[r][16] = m;
  }
  __syncthreads();
  mx = red[r][16];
  float sm = 0.f;
  for (int j = cc; j < SEQ; j += 16) {
    float e = expf(Ss[r][j] - mx);
    Ss[r][j] = e;
    sm += e;
  }
  __syncthreads();
  red[r][cc] = sm;
  __syncthreads();
  if (cc == 0) {
    float s = 0.f;
#pragma unroll
    for (int j = 0; j < 16; j++) s += red[r][j];
    red[r][16] = s;
  }
  __syncthreads();
  float inv = 1.0f / red[r][16];
  for (int j = cc; j < SEQ; j += 16) Ss[r][j] *= inv;
  // PV
  int dd = cc * 4;
  float a0 = 0.f, a1 = 0.f, a2 = 0.f, a3 = 0.f;
  for (int kc = 0; kc < SEQ; kc += 32) {
    __syncthreads();
#pragma unroll
    for (int c = 0; c < 8; c++) {
      int e = c * 256 + t, rr = e >> 6, d = e & 63;
      Vs[rr][d] = qkv[(size_t)(b * SEQ + kc + rr) * 768 + 512 + h * 64 + d];
    }
    __syncthreads();
#pragma unroll
    for (int kk = 0; kk < 32; kk++) {
      float p = Ss[r][kc + kk];
      a0 += p * Vs[kk][dd + 0];
      a1 += p * Vs[kk][dd + 1];
      a2 += p * Vs[kk][dd + 2];
      a3 += p * Vs[kk][dd + 3];
    }
  }
  int row = b * SEQ + s0 + r;
  size_t base = (size_t)row * 2304;
  float av[4] = {a0, a1, a2, a3};
#pragma unroll
  for (int j = 0; j < 4; j++) {
    int col = h * 64 + dd + j;
    u16 s; us8 u;
    expand9(av[j], &s, &u);
    Xe[base + col] = s;
    *(us8*)(Xe + base + 256 + (size_t)col * 8) = u;
  }
}

// ---------- launch ----------

extern "C" void kernel_launch(void* const* d_in, const int* in_sizes, int n_in,
                              void* d_out, int out_size, void* d_ws, size_t ws_size,
                              hipStream_t stream) {
  const int* ids = (const int*)d_in[0];
  const float* wemb = (const float*)d_in[1];
  const float* ttemb = (const float*)d_in[2];
  const float* pemb = (const float*)d_in[3];
  const float* elg = (const float*)d_in[4];
  const float* elb = (const float*)d_in[5];
  const float* qb = (const float*)d_in[6], *qs = (const float*)d_in[7];
  const float* kb = (const float*)d_in[8], *ks = (const float*)d_in[9];
  const float* vb = (const float*)d_in[10], *vs = (const float*)d_in[11];
  const float* ob = (const float*)d_in[12], *osp = (const float*)d_in[13];
  const float* f1b = (const float*)d_in[14], *f1s = (const float*)d_in[15];
  const float* f2b = (const float*)d_in[16], *f2s = (const float*)d_in[17];
  const float* l1g = (const float*)d_in[18], *l1b = (const float*)d_in[19];
  const float* l2g = (const float*)d_in[20], *l2b = (const float*)d_in[21];
  const float* hkb = (const float*)d_in[22], *hks = (const float*)d_in[23];
  const float* hob = (const float*)d_in[24], *hos = (const float*)d_in[25];
  float* out = (float*)d_out;

  char* w = (char*)d_ws;
  const size_t MB = 1 << 20;
  float* xbuf = (float*)(w);                 // 1 MB  [1024*256]
  float* tmp  = (float*)(w + 1 * MB);        // 1 MB  (head LN scratch)
  float* qkv  = (float*)(w + 2 * MB);        // 3 MB  [1024*768]
  float* part = (float*)(w + 5 * MB);        // 4 MB  [4][1024*256] split-K partials
  float* ff1  = (float*)(w + 9 * MB);        // 4 MB  [1024*1024]
  u16*   Xe2  = (u16*)  (w + 13 * MB);       // 18 MB [1024*9216]   f1-out expansion
  u16*   Xe   = (u16*)  (w + 31 * MB);       // 4.5MB [1024*2304]
  u16*   Wc   = (u16*)  (w + 36 * MB);       // 196 MB packed bf16 weights

  const size_t oq = 0, okk = 2359296, ov = 4718592, oo = 7077888;
  const size_t of1 = 9437184, of2 = 18874368, ohk = 28311552, oho = 28901376;

  {
    PackA pa;
    pa.b[0] = qb;  pa.s[0] = qs;  pa.off[0] = oq;  pa.shift[0] = 8;
    pa.b[1] = kb;  pa.s[1] = ks;  pa.off[1] = okk; pa.shift[1] = 8;
    pa.b[2] = vb;  pa.s[2] = vs;  pa.off[2] = ov;  pa.shift[2] = 8;
    pa.b[3] = ob;  pa.s[3] = osp; pa.off[3] = oo;  pa.shift[3] = 8;
    pa.b[4] = f1b; pa.s[4] = f1s; pa.off[4] = of1; pa.shift[4] = 8;
    pa.b[5] = f2b; pa.s[5] = f2s; pa.off[5] = of2; pa.shift[5] = 10;
    pa.b[6] = hkb; pa.s[6] = hks; pa.off[6] = ohk; pa.shift[6] = 8;
    pa.b[7] = hob; pa.s[7] = hos; pa.off[7] = oho; pa.shift[7] = 8;
    long long cum = 0;
    long long sz[8] = {262144, 262144, 262144, 262144, 1048576, 1048576, 65536, 8192000};
    for (int i = 0; i < 8; i++) { pa.cum[i] = cum; cum += sz[i]; }
    pa.cum[8] = cum;                          // 11,403,264 elems
    pack_all<<<(unsigned)((cum + 255) / 256), 256, 0, stream>>>(pa, Wc);
  }

  embed_ln_x<<<TOKENS, 256, 0, stream>>>(ids, wemb, ttemb, pemb, elg, elb, xbuf, Xe);

  for (int l = 0; l < 4; l++) {
    const size_t wl = (size_t)l * 589824, fl = (size_t)l * 2359296;

    gemm_b16<64, 64, 2><<<dim3(16, 12), 256, 0, stream>>>(
        Xe, Wc + oq + wl, Wc + okk + wl, Wc + ov + wl, 256, 768, 2304, 2304, qkv);
    attn_fused<<<dim3(8, 32), 256, 0, stream>>>(qkv, Xe);
    gemm_b16<64, 64, 2><<<dim3(16, 4, 2), 256, 0, stream>>>(
        Xe, Wc + oo + wl, Wc + oo + wl, Wc + oo + wl, 256, 256, 2304, 1152, part);
    add_ln_x<<<TOKENS, 256, 0, stream>>>(part, 2, TOKENS * 256, xbuf,
                                         l1g + l * 256, l1b + l * 256, 1e-5f, 0, xbuf, Xe);
    gemm_b16<64, 64, 2><<<dim3(16, 16), 256, 0, stream>>>(
        Xe, Wc + of1 + fl, Wc + of1 + fl, Wc + of1 + fl, 1024, 1024, 2304, 2304, ff1);
    expand_ff<<<4096, 256, 0, stream>>>(ff1, Xe2);
    gemm_b16<64, 64, 2><<<dim3(16, 4, 4), 256, 0, stream>>>(
        Xe2, Wc + of2 + fl, Wc + of2 + fl, Wc + of2 + fl, 256, 256, 9216, 2304, part);
    add_ln_x<<<TOKENS, 256, 0, stream>>>(part, 4, TOKENS * 256, xbuf,
                                         l2g + l * 256, l2b + l * 256, 1e-5f, 0, xbuf, Xe);
  }

  // head: KAN -> gelu -> LN(no affine, eps 1e-12) -> KAN to vocab
  gemm_b16<64, 64, 2><<<dim3(16, 4, 2), 256, 0, stream>>>(
      Xe, Wc + ohk, Wc + ohk, Wc + ohk, 256, 256, 2304, 1152, part);
  add_ln_x<<<TOKENS, 256, 0, stream>>>(part, 2, TOKENS * 256, nullptr, nullptr, nullptr,
                                       1e-12f, 1, tmp, Xe);
  gemm_b16<128, 128, 1><<<dim3(8, 250), 256, 0, stream>>>(
      Xe, Wc + oho, Wc + oho, Wc + oho, 32000, 32000, 2304, 2304, out);
}

// Round 7
// 1037.483 us; speedup vs baseline: 2.9165x; 1.1561x over previous
//
#include <hip/hip_runtime.h>
#include <math.h>

typedef unsigned short u16;
typedef unsigned int u32;
typedef __bf16 bf16x8 __attribute__((ext_vector_type(8)));
typedef float f32x4 __attribute__((ext_vector_type(4)));
typedef u16 us8 __attribute__((ext_vector_type(8)));

#define TOKENS 1024
#define DIM 256
#define SEQ 512

// ---------- helpers ----------

__device__ __forceinline__ u16 f2bf(float f) {
  u32 x = __float_as_uint(f);
  x += 0x7fffu + ((x >> 16) & 1u);
  return (u16)(x >> 16);
}

// silu + 8 cubic B-spline bases, uniform extended grid g[j] = (j-3)*0.4f - 1.0f.
// Compile-time-reciprocal Cox-de Boor (denominators constant).
__device__ __forceinline__ void expand9(float x, u16* sil, us8* u) {
  float sig = 1.0f / (1.0f + expf(-x));
  *sil = f2bf(x * sig);
  float bs[11];
#pragma unroll
  for (int j = 0; j < 11; j++) {
    float gj  = (float)(j - 3) * 0.4f - 1.0f;
    float gj1 = (float)(j - 2) * 0.4f - 1.0f;
    bs[j] = (x >= gj && x < gj1) ? 1.0f : 0.0f;
  }
#pragma unroll
  for (int k = 1; k <= 3; k++) {
#pragma unroll
    for (int j = 0; j < 10; j++) {
      if (j + k < 11) {
        float gj   = (float)(j - 3) * 0.4f - 1.0f;
        float gj1  = (float)(j - 2) * 0.4f - 1.0f;
        float gjk  = (float)(j + k - 3) * 0.4f - 1.0f;
        float gjk1 = (float)(j + k - 2) * 0.4f - 1.0f;
        float linv = 1.0f / (gjk - gj);
        float rinv = 1.0f / (gjk1 - gj1);
        bs[j] = (x - gj) * linv * bs[j] + (gjk1 - x) * rinv * bs[j + 1];
      }
    }
  }
#pragma unroll
  for (int c = 0; c < 8; c++) (*u)[c] = f2bf(bs[c]);
}

// 256-thread block sum (4 waves of 64)
__device__ __forceinline__ float block_sum_256(float v) {
  __shared__ float red[4];
  int t = threadIdx.x, lane = t & 63, wid = t >> 6;
#pragma unroll
  for (int o = 32; o > 0; o >>= 1) v += __shfl_down(v, o, 64);
  __syncthreads();
  if (lane == 0) red[wid] = v;
  __syncthreads();
  return red[0] + red[1] + red[2] + red[3];
}

// ---------- embedding + LN (eps 1e-12) + expand ----------

__global__ void embed_ln_x(const int* __restrict__ ids, const float* __restrict__ wemb,
                           const float* __restrict__ tt, const float* __restrict__ pe,
                           const float* __restrict__ g, const float* __restrict__ bta,
                           float* __restrict__ xout, u16* __restrict__ Xe) {
  int row = blockIdx.x, t = threadIdx.x;
  int id = ids[row];
  float v = wemb[(size_t)id * DIM + t] + tt[DIM + t] + pe[DIM + t];
  float mu = block_sum_256(v) * (1.0f / 256.0f);
  float d = v - mu;
  float var = block_sum_256(d * d) * (1.0f / 256.0f);
  float y = d * rsqrtf(var + 1e-12f) * g[t] + bta[t];
  xout[(size_t)row * DIM + t] = y;
  size_t base = (size_t)row * 2304;
  u16 s; us8 u;
  expand9(y, &s, &u);
  Xe[base + t] = s;
  *(us8*)(Xe + base + 256 + (size_t)t * 8) = u;
}

// ---------- (sum of nsum partials) [+gelu] [+res] + LN + expand ----------

__global__ void add_ln_x(const float* __restrict__ a, int nsum, int sstride,
                         const float* __restrict__ res,
                         const float* __restrict__ g, const float* __restrict__ bta,
                         float eps, int dogelu,
                         float* __restrict__ xout, u16* __restrict__ Xe) {
  int row = blockIdx.x, t = threadIdx.x;
  int idx = row * 256 + t;
  float v = 0.f;
  for (int s = 0; s < nsum; s++) v += a[(size_t)s * sstride + idx];
  if (dogelu) v = 0.5f * v * (1.0f + erff(v * 0.70710678118654752f));
  if (res) v += res[idx];
  float mu = block_sum_256(v) * (1.0f / 256.0f);
  float d = v - mu;
  float var = block_sum_256(d * d) * (1.0f / 256.0f);
  float y = d * rsqrtf(var + eps);
  if (g) y = y * g[t] + bta[t];
  xout[idx] = y;
  size_t base = (size_t)row * 2304;
  u16 s16; us8 u;
  expand9(y, &s16, &u);
  Xe[base + t] = s16;
  *(us8*)(Xe + base + 256 + (size_t)t * 8) = u;
}

// ---------- relu + expand for FF hidden: ff1[1024,1024] f32 -> Xe2[1024, 9216] bf16 ----------

__global__ void expand_ff(const float* __restrict__ X, u16* __restrict__ Xe) {
  int idx = blockIdx.x * 256 + threadIdx.x;
  int n = idx >> 10, i = idx & 1023;
  float x = fmaxf(X[idx], 0.0f);
  u16 s; us8 u;
  expand9(x, &s, &u);
  size_t base = (size_t)n * 9216;
  Xe[base + i] = s;
  *(us8*)(Xe + base + 1024 + (size_t)i * 8) = u;
}

// ---------- GEMM: C[1024,N] = A[1024,K](bf16) @ Wvirt[N,K]^T, W = [base|spline] f32 ----------
// f32 weights converted RNE->bf16 during staging (no pre-pack: each weight used once).
// XCD-contiguous remap, XOR-swizzled LDS, named-register prefetch pipeline.
// blockIdx.z = K-split slice (kchunk cols, must be multiple of BK); partial C at z*TOKENS*N.
// Staging geometry (both configs): 4 A-chunks (bf16, 1 uint4 each) + 4 B-chunks (f32, 2 float4 each).

#define LDA4(c, v) { int r_ = (c) * RPC + (t >> LGP); int g_ = t & (GPB - 1); \
    v = *(const uint4*)(A + (size_t)(m0 + r_) * K + k0n + g_ * 8); }
#define LDB4(c, va, vb) { int r_ = (c) * RPC + (t >> LGP); int g_ = t & (GPB - 1); \
    int kv_ = k0n + g_ * 8; \
    const float* p_ = (kv_ < infeat) ? (Wb + (size_t)(onb + r_) * infeat + kv_) \
                                     : (Ws + (size_t)(onb + r_) * infeat * 8 + (kv_ - infeat)); \
    va = *(const float4*)p_; vb = *(const float4*)(p_ + 4); }
#define STA4(c, v) { int r_ = (c) * RPC + (t >> LGP); int g_ = t & (GPB - 1); \
    *(uint4*)(&As[r_ * BK + ((g_ ^ (r_ & (GPB - 1))) << 3)]) = v; }
#define STB4(c, va, vb) { int r_ = (c) * RPC + (t >> LGP); int g_ = t & (GPB - 1); \
    bf16x8 h_; \
    h_[0] = (__bf16)va.x; h_[1] = (__bf16)va.y; h_[2] = (__bf16)va.z; h_[3] = (__bf16)va.w; \
    h_[4] = (__bf16)vb.x; h_[5] = (__bf16)vb.y; h_[6] = (__bf16)vb.z; h_[7] = (__bf16)vb.w; \
    *(bf16x8*)(&Bs[r_ * BK + ((g_ ^ (r_ & (GPB - 1))) << 3)]) = h_; }

template <int BM, int BN, int BK, int MINW>
__global__ __launch_bounds__(256, MINW)
void gemm_kw(const u16* __restrict__ A,
             const float* __restrict__ b0, const float* __restrict__ s0,
             const float* __restrict__ b1, const float* __restrict__ s1,
             const float* __restrict__ b2, const float* __restrict__ s2,
             int nper, int N, int K, int infeat, int kchunk, float* __restrict__ C) {
  constexpr int GPB = BK / 8;                // 8-col groups per row
  constexpr int LGP = (GPB == 8) ? 3 : 4;
  constexpr int RPC = 256 / GPB;             // rows per staging chunk
  static_assert(BM / RPC == 4 && BN / RPC == 4, "need exactly 4+4 chunks");
  constexpr int FM = BM / 32, FN = BN / 32;
  __shared__ u16 As[BM * BK];
  __shared__ u16 Bs[BN * BK];
  const int gx = gridDim.x;
  const int nwg = gx * gridDim.y;
  int g = blockIdx.y * gx + blockIdx.x;
  int lin = g;
  if ((nwg & 7) == 0) lin = (g & 7) * (nwg >> 3) + (g >> 3);
  const int m0 = (lin % gx) * BM;
  const int n0 = (lin / gx) * BN;
  const int z = blockIdx.z;
  const int kbeg = z * kchunk;
  const int kend = (kbeg + kchunk < K) ? kbeg + kchunk : K;
  const int t = threadIdx.x;
  const int lane = t & 63, wid = t >> 6;
  const int wm = (wid >> 1) * (BM / 2), wn = (wid & 1) * (BN / 2);
  const int proj = n0 / nper;
  const float* Wb = proj == 0 ? b0 : (proj == 1 ? b1 : b2);
  const float* Ws = proj == 0 ? s0 : (proj == 1 ? s1 : s2);
  const int onb = n0 - proj * nper;

  f32x4 acc[FM][FN];
#pragma unroll
  for (int i = 0; i < FM; i++)
#pragma unroll
    for (int j = 0; j < FN; j++) acc[i][j] = (f32x4){0.f, 0.f, 0.f, 0.f};

  const int frow = lane & 15;
  const int cgrp = lane >> 4;

  uint4 pa0, pa1, pa2, pa3;
  float4 pb0a, pb0b, pb1a, pb1b, pb2a, pb2b, pb3a, pb3b;
  int k0n = kbeg;
  LDA4(0, pa0); LDA4(1, pa1); LDA4(2, pa2); LDA4(3, pa3);
  LDB4(0, pb0a, pb0b); LDB4(1, pb1a, pb1b); LDB4(2, pb2a, pb2b); LDB4(3, pb3a, pb3b);

  for (int k0 = kbeg; k0 < kend; k0 += BK) {
    STA4(0, pa0); STA4(1, pa1); STA4(2, pa2); STA4(3, pa3);
    STB4(0, pb0a, pb0b); STB4(1, pb1a, pb1b); STB4(2, pb2a, pb2b); STB4(3, pb3a, pb3b);
    __syncthreads();
    if (k0 + BK < kend) {                     // prefetch next tile into named registers
      k0n = k0 + BK;
      LDA4(0, pa0); LDA4(1, pa1); LDA4(2, pa2); LDA4(3, pa3);
      LDB4(0, pb0a, pb0b); LDB4(1, pb1a, pb1b); LDB4(2, pb2a, pb2b); LDB4(3, pb3a, pb3b);
    }
#pragma unroll
    for (int kk = 0; kk < BK; kk += 32) {
      bf16x8 af[FM], bfr[FN];
#pragma unroll
      for (int i = 0; i < FM; i++) {
        int rr = wm + i * 16 + frow;
        int ch = (kk >> 3) + cgrp;
        af[i] = *reinterpret_cast<const bf16x8*>(&As[rr * BK + ((ch ^ (rr & (GPB - 1))) << 3)]);
      }
#pragma unroll
      for (int j = 0; j < FN; j++) {
        int rr = wn + j * 16 + frow;
        int ch = (kk >> 3) + cgrp;
        bfr[j] = *reinterpret_cast<const bf16x8*>(&Bs[rr * BK + ((ch ^ (rr & (GPB - 1))) << 3)]);
      }
#pragma unroll
      for (int i = 0; i < FM; i++)
#pragma unroll
        for (int j = 0; j < FN; j++)
          acc[i][j] = __builtin_amdgcn_mfma_f32_16x16x32_bf16(af[i], bfr[j], acc[i][j], 0, 0, 0);
    }
    __syncthreads();
  }

  const int crow = (lane >> 4) * 4;
  const int ccol = lane & 15;
  float* Cz = C + (size_t)z * TOKENS * N;
#pragma unroll
  for (int i = 0; i < FM; i++)
#pragma unroll
    for (int j = 0; j < FN; j++) {
      int row = m0 + wm + i * 16 + crow;
      int col = n0 + wn + j * 16 + ccol;
#pragma unroll
      for (int r = 0; r < 4; r++)
        Cz[(size_t)(row + r) * N + col] = acc[i][j][r];
    }
}

// ---------- fused attention: QK^T + softmax + PV + KAN-expand (P stays in LDS) ----------

__global__ void attn_fused(const float* __restrict__ qkv, u16* __restrict__ Xe) {
  int bh = blockIdx.x, b = bh >> 2, h = bh & 3;
  int s0 = blockIdx.y * 16;
  int t = threadIdx.x;
  __shared__ float Qs[16][64];
  __shared__ float Ks[16][65];
  __shared__ float Ss[16][513];
  __shared__ float red[16][17];
  __shared__ float Vs[32][65];
#pragma unroll
  for (int c = 0; c < 4; c++) {
    int e = c * 256 + t, r = e >> 6, d = e & 63;
    Qs[r][d] = qkv[(size_t)(b * SEQ + s0 + r) * 768 + h * 64 + d];
  }
  int r = t >> 4, cc = t & 15;
  for (int kc = 0; kc < SEQ; kc += 16) {
    __syncthreads();
#pragma unroll
    for (int c = 0; c < 4; c++) {
      int e = c * 256 + t, rr = e >> 6, d = e & 63;
      Ks[rr][d] = qkv[(size_t)(b * SEQ + kc + rr) * 768 + 256 + h * 64 + d];
    }
    __syncthreads();
    float acc = 0.f;
#pragma unroll
    for (int d = 0; d < 64; d++) acc += Qs[r][d] * Ks[cc][d];
    Ss[r][kc + cc] = acc * 0.125f;
  }
  __syncthreads();
  float mx = -3.4e38f;
  for (int j = cc; j < SEQ; j += 16) mx = fmaxf(mx, Ss[r][j]);
  red[r][cc] = mx;
  __syncthreads();
  if (cc == 0) {
    float m = red[r][0];
#pragma unroll
    for (int j = 1; j < 16; j++) m = fmaxf(m, red[r][j]);
    red[r][16] = m;
  }
  __syncthreads();
  mx = red[r][16];
  float sm = 0.f;
  for (int j = cc; j < SEQ; j += 16) {
    float e = expf(Ss[r][j] - mx);
    Ss[r][j] = e;
    sm += e;
  }
  __syncthreads();
  red[r][cc] = sm;
  __syncthreads();
  if (cc == 0) {
    float s = 0.f;
#pragma unroll
    for (int j = 0; j < 16; j++) s += red[r][j];
    red[r][16] = s;
  }
  __syncthreads();
  float inv = 1.0f / red[r][16];
  for (int j = cc; j < SEQ; j += 16) Ss[r][j] *= inv;
  // PV
  int dd = cc * 4;
  float a0 = 0.f, a1 = 0.f, a2 = 0.f, a3 = 0.f;
  for (int kc = 0; kc < SEQ; kc += 32) {
    __syncthreads();
#pragma unroll
    for (int c = 0; c < 8; c++) {
      int e = c * 256 + t, rr = e >> 6, d = e & 63;
      Vs[rr][d] = qkv[(size_t)(b * SEQ + kc + rr) * 768 + 512 + h * 64 + d];
    }
    __syncthreads();
#pragma unroll
    for (int kk = 0; kk < 32; kk++) {
      float p = Ss[r][kc + kk];
      a0 += p * Vs[kk][dd + 0];
      a1 += p * Vs[kk][dd + 1];
      a2 += p * Vs[kk][dd + 2];
      a3 += p * Vs[kk][dd + 3];
    }
  }
  int row = b * SEQ + s0 + r;
  size_t base = (size_t)row * 2304;
  float av[4] = {a0, a1, a2, a3};
#pragma unroll
  for (int j = 0; j < 4; j++) {
    int col = h * 64 + dd + j;
    u16 s; us8 u;
    expand9(av[j], &s, &u);
    Xe[base + col] = s;
    *(us8*)(Xe + base + 256 + (size_t)col * 8) = u;
  }
}

// ---------- launch ----------

extern "C" void kernel_launch(void* const* d_in, const int* in_sizes, int n_in,
                              void* d_out, int out_size, void* d_ws, size_t ws_size,
                              hipStream_t stream) {
  const int* ids = (const int*)d_in[0];
  const float* wemb = (const float*)d_in[1];
  const float* ttemb = (const float*)d_in[2];
  const float* pemb = (const float*)d_in[3];
  const float* elg = (const float*)d_in[4];
  const float* elb = (const float*)d_in[5];
  const float* qb = (const float*)d_in[6], *qs = (const float*)d_in[7];
  const float* kb = (const float*)d_in[8], *ks = (const float*)d_in[9];
  const float* vb = (const float*)d_in[10], *vs = (const float*)d_in[11];
  const float* ob = (const float*)d_in[12], *osp = (const float*)d_in[13];
  const float* f1b = (const float*)d_in[14], *f1s = (const float*)d_in[15];
  const float* f2b = (const float*)d_in[16], *f2s = (const float*)d_in[17];
  const float* l1g = (const float*)d_in[18], *l1b = (const float*)d_in[19];
  const float* l2g = (const float*)d_in[20], *l2b = (const float*)d_in[21];
  const float* hkb = (const float*)d_in[22], *hks = (const float*)d_in[23];
  const float* hob = (const float*)d_in[24], *hos = (const float*)d_in[25];
  float* out = (float*)d_out;

  char* w = (char*)d_ws;
  const size_t MB = 1 << 20;
  float* xbuf = (float*)(w);                 // 1 MB  [1024*256]
  float* tmp  = (float*)(w + 1 * MB);        // 1 MB  (head LN scratch)
  float* qkv  = (float*)(w + 2 * MB);        // 3 MB  [1024*768]
  float* part = (float*)(w + 5 * MB);        // 4 MB  [4][1024*256] split-K partials
  float* ff1  = (float*)(w + 9 * MB);        // 4 MB  [1024*1024]
  u16*   Xe2  = (u16*)  (w + 13 * MB);       // 18 MB [1024*9216]   f1-out expansion
  u16*   Xe   = (u16*)  (w + 31 * MB);       // 4.5MB [1024*2304]

  embed_ln_x<<<TOKENS, 256, 0, stream>>>(ids, wemb, ttemb, pemb, elg, elb, xbuf, Xe);

  for (int l = 0; l < 4; l++) {
    const float* qbl = qb + (size_t)l * 65536, *qsl = qs + (size_t)l * 524288;
    const float* kbl = kb + (size_t)l * 65536, *ksl = ks + (size_t)l * 524288;
    const float* vbl = vb + (size_t)l * 65536, *vsl = vs + (size_t)l * 524288;
    const float* obl = ob + (size_t)l * 65536, *osl = osp + (size_t)l * 524288;
    const float* f1bl = f1b + (size_t)l * 262144, *f1sl = f1s + (size_t)l * 2097152;
    const float* f2bl = f2b + (size_t)l * 262144, *f2sl = f2s + (size_t)l * 2097152;

    gemm_kw<64, 64, 128, 2><<<dim3(16, 12), 256, 0, stream>>>(
        Xe, qbl, qsl, kbl, ksl, vbl, vsl, 256, 768, 2304, 256, 2304, qkv);
    attn_fused<<<dim3(8, 32), 256, 0, stream>>>(qkv, Xe);
    gemm_kw<64, 64, 128, 2><<<dim3(16, 4, 4), 256, 0, stream>>>(
        Xe, obl, osl, obl, osl, obl, osl, 256, 256, 2304, 256, 640, part);
    add_ln_x<<<TOKENS, 256, 0, stream>>>(part, 4, TOKENS * 256, xbuf,
                                         l1g + l * 256, l1b + l * 256, 1e-5f, 0, xbuf, Xe);
    gemm_kw<64, 64, 128, 2><<<dim3(16, 16), 256, 0, stream>>>(
        Xe, f1bl, f1sl, f1bl, f1sl, f1bl, f1sl, 1024, 1024, 2304, 256, 2304, ff1);
    expand_ff<<<4096, 256, 0, stream>>>(ff1, Xe2);
    gemm_kw<64, 64, 128, 2><<<dim3(16, 4, 4), 256, 0, stream>>>(
        Xe2, f2bl, f2sl, f2bl, f2sl, f2bl, f2sl, 256, 256, 9216, 1024, 2304, part);
    add_ln_x<<<TOKENS, 256, 0, stream>>>(part, 4, TOKENS * 256, xbuf,
                                         l2g + l * 256, l2b + l * 256, 1e-5f, 0, xbuf, Xe);
  }

  // head: KAN -> gelu -> LN(no affine, eps 1e-12) -> KAN to vocab
  gemm_kw<64, 64, 128, 2><<<dim3(16, 4, 4), 256, 0, stream>>>(
      Xe, hkb, hks, hkb, hks, hkb, hks, 256, 256, 2304, 256, 640, part);
  add_ln_x<<<TOKENS, 256, 0, stream>>>(part, 4, TOKENS * 256, nullptr, nullptr, nullptr,
                                       1e-12f, 1, tmp, Xe);
  gemm_kw<128, 128, 64, 1><<<dim3(8, 250), 256, 0, stream>>>(
      Xe, hob, hos, hob, hos, hob, hos, 32000, 32000, 2304, 256, 2304, out);
}

// Round 8
// 1033.039 us; speedup vs baseline: 2.9290x; 1.0043x over previous
//
#include <hip/hip_runtime.h>
#include <math.h>

typedef unsigned short u16;
typedef unsigned int u32;
typedef __bf16 bf16x8 __attribute__((ext_vector_type(8)));
typedef float f32x4 __attribute__((ext_vector_type(4)));
typedef u16 us8 __attribute__((ext_vector_type(8)));

#define TOKENS 1024
#define DIM 256
#define SEQ 512

// ---------- helpers ----------

__device__ __forceinline__ u16 f2bf(float f) {
  u32 x = __float_as_uint(f);
  x += 0x7fffu + ((x >> 16) & 1u);
  return (u16)(x >> 16);
}

// silu + 8 cubic B-spline bases, uniform extended grid g[j] = (j-3)*0.4f - 1.0f.
// Compile-time-reciprocal Cox-de Boor (denominators constant).
__device__ __forceinline__ void expand9(float x, u16* sil, us8* u) {
  float sig = 1.0f / (1.0f + expf(-x));
  *sil = f2bf(x * sig);
  float bs[11];
#pragma unroll
  for (int j = 0; j < 11; j++) {
    float gj  = (float)(j - 3) * 0.4f - 1.0f;
    float gj1 = (float)(j - 2) * 0.4f - 1.0f;
    bs[j] = (x >= gj && x < gj1) ? 1.0f : 0.0f;
  }
#pragma unroll
  for (int k = 1; k <= 3; k++) {
#pragma unroll
    for (int j = 0; j < 10; j++) {
      if (j + k < 11) {
        float gj   = (float)(j - 3) * 0.4f - 1.0f;
        float gj1  = (float)(j - 2) * 0.4f - 1.0f;
        float gjk  = (float)(j + k - 3) * 0.4f - 1.0f;
        float gjk1 = (float)(j + k - 2) * 0.4f - 1.0f;
        float linv = 1.0f / (gjk - gj);
        float rinv = 1.0f / (gjk1 - gj1);
        bs[j] = (x - gj) * linv * bs[j] + (gjk1 - x) * rinv * bs[j + 1];
      }
    }
  }
#pragma unroll
  for (int c = 0; c < 8; c++) (*u)[c] = f2bf(bs[c]);
}

// 256-thread block sum (4 waves of 64)
__device__ __forceinline__ float block_sum_256(float v) {
  __shared__ float red[4];
  int t = threadIdx.x, lane = t & 63, wid = t >> 6;
#pragma unroll
  for (int o = 32; o > 0; o >>= 1) v += __shfl_down(v, o, 64);
  __syncthreads();
  if (lane == 0) red[wid] = v;
  __syncthreads();
  return red[0] + red[1] + red[2] + red[3];
}

// ---------- embedding + LN (eps 1e-12) + expand ----------

__global__ void embed_ln_x(const int* __restrict__ ids, const float* __restrict__ wemb,
                           const float* __restrict__ tt, const float* __restrict__ pe,
                           const float* __restrict__ g, const float* __restrict__ bta,
                           float* __restrict__ xout, u16* __restrict__ Xe) {
  int row = blockIdx.x, t = threadIdx.x;
  int id = ids[row];
  float v = wemb[(size_t)id * DIM + t] + tt[DIM + t] + pe[DIM + t];
  float mu = block_sum_256(v) * (1.0f / 256.0f);
  float d = v - mu;
  float var = block_sum_256(d * d) * (1.0f / 256.0f);
  float y = d * rsqrtf(var + 1e-12f) * g[t] + bta[t];
  xout[(size_t)row * DIM + t] = y;
  size_t base = (size_t)row * 2304;
  u16 s; us8 u;
  expand9(y, &s, &u);
  Xe[base + t] = s;
  *(us8*)(Xe + base + 256 + (size_t)t * 8) = u;
}

// ---------- (sum of nsum partials) [+gelu] [+res] + LN + expand ----------

__global__ void add_ln_x(const float* __restrict__ a, int nsum, int sstride,
                         const float* __restrict__ res,
                         const float* __restrict__ g, const float* __restrict__ bta,
                         float eps, int dogelu,
                         float* __restrict__ xout, u16* __restrict__ Xe) {
  int row = blockIdx.x, t = threadIdx.x;
  int idx = row * 256 + t;
  float v = 0.f;
  for (int s = 0; s < nsum; s++) v += a[(size_t)s * sstride + idx];
  if (dogelu) v = 0.5f * v * (1.0f + erff(v * 0.70710678118654752f));
  if (res) v += res[idx];
  float mu = block_sum_256(v) * (1.0f / 256.0f);
  float d = v - mu;
  float var = block_sum_256(d * d) * (1.0f / 256.0f);
  float y = d * rsqrtf(var + eps);
  if (g) y = y * g[t] + bta[t];
  xout[idx] = y;
  size_t base = (size_t)row * 2304;
  u16 s16; us8 u;
  expand9(y, &s16, &u);
  Xe[base + t] = s16;
  *(us8*)(Xe + base + 256 + (size_t)t * 8) = u;
}

// ---------- GEMM: C[1024,N] = A[1024,K](bf16) @ Wvirt[N,K]^T, W = [base|spline] f32 ----------
// f32 weights converted RNE->bf16 during staging. XCD-contiguous remap, XOR-swizzled
// LDS, named-register prefetch pipeline. blockIdx.z = K-split slice (kchunk, multiple
// of BK); partial C at z*TOKENS*N. EPI: 0 = f32 store; 1 = relu+KAN-expand into XeOut.

#define LDA4(c, v) { int r_ = (c) * RPC + (t >> LGP); int g_ = t & (GPB - 1); \
    v = *(const uint4*)(A + (size_t)(m0 + r_) * K + k0n + g_ * 8); }
#define LDB4(c, va, vb) { int r_ = (c) * RPC + (t >> LGP); int g_ = t & (GPB - 1); \
    int kv_ = k0n + g_ * 8; \
    const float* p_ = (kv_ < infeat) ? (Wb + (size_t)(onb + r_) * infeat + kv_) \
                                     : (Ws + (size_t)(onb + r_) * infeat * 8 + (kv_ - infeat)); \
    va = *(const float4*)p_; vb = *(const float4*)(p_ + 4); }
#define STA4(c, v) { int r_ = (c) * RPC + (t >> LGP); int g_ = t & (GPB - 1); \
    *(uint4*)(&As[r_ * BK + ((g_ ^ (r_ & (GPB - 1))) << 3)]) = v; }
#define STB4(c, va, vb) { int r_ = (c) * RPC + (t >> LGP); int g_ = t & (GPB - 1); \
    bf16x8 h_; \
    h_[0] = (__bf16)va.x; h_[1] = (__bf16)va.y; h_[2] = (__bf16)va.z; h_[3] = (__bf16)va.w; \
    h_[4] = (__bf16)vb.x; h_[5] = (__bf16)vb.y; h_[6] = (__bf16)vb.z; h_[7] = (__bf16)vb.w; \
    *(bf16x8*)(&Bs[r_ * BK + ((g_ ^ (r_ & (GPB - 1))) << 3)]) = h_; }

template <int BM, int BN, int BK, int MINW, int EPI>
__global__ __launch_bounds__(256, MINW)
void gemm_kw(const u16* __restrict__ A,
             const float* __restrict__ b0, const float* __restrict__ s0,
             const float* __restrict__ b1, const float* __restrict__ s1,
             const float* __restrict__ b2, const float* __restrict__ s2,
             int nper, int N, int K, int infeat, int kchunk, float* __restrict__ C,
             u16* __restrict__ XeOut, int infOut) {
  constexpr int GPB = BK / 8;                // 8-col groups per row
  constexpr int LGP = (GPB == 8) ? 3 : 4;
  constexpr int RPC = 256 / GPB;             // rows per staging chunk
  static_assert(BM / RPC == 4 && BN / RPC == 4, "need exactly 4+4 chunks");
  constexpr int FM = BM / 32, FN = BN / 32;
  __shared__ u16 As[BM * BK];
  __shared__ u16 Bs[BN * BK];
  const int gx = gridDim.x;
  const int nwg = gx * gridDim.y;
  int g = blockIdx.y * gx + blockIdx.x;
  int lin = g;
  if ((nwg & 7) == 0) lin = (g & 7) * (nwg >> 3) + (g >> 3);
  const int m0 = (lin % gx) * BM;
  const int n0 = (lin / gx) * BN;
  const int z = blockIdx.z;
  const int kbeg = z * kchunk;
  const int kend = (kbeg + kchunk < K) ? kbeg + kchunk : K;
  const int t = threadIdx.x;
  const int lane = t & 63, wid = t >> 6;
  const int wm = (wid >> 1) * (BM / 2), wn = (wid & 1) * (BN / 2);
  const int proj = n0 / nper;
  const float* Wb = proj == 0 ? b0 : (proj == 1 ? b1 : b2);
  const float* Ws = proj == 0 ? s0 : (proj == 1 ? s1 : s2);
  const int onb = n0 - proj * nper;

  f32x4 acc[FM][FN];
#pragma unroll
  for (int i = 0; i < FM; i++)
#pragma unroll
    for (int j = 0; j < FN; j++) acc[i][j] = (f32x4){0.f, 0.f, 0.f, 0.f};

  const int frow = lane & 15;
  const int cgrp = lane >> 4;

  uint4 pa0, pa1, pa2, pa3;
  float4 pb0a, pb0b, pb1a, pb1b, pb2a, pb2b, pb3a, pb3b;
  int k0n = kbeg;
  LDA4(0, pa0); LDA4(1, pa1); LDA4(2, pa2); LDA4(3, pa3);
  LDB4(0, pb0a, pb0b); LDB4(1, pb1a, pb1b); LDB4(2, pb2a, pb2b); LDB4(3, pb3a, pb3b);

  for (int k0 = kbeg; k0 < kend; k0 += BK) {
    STA4(0, pa0); STA4(1, pa1); STA4(2, pa2); STA4(3, pa3);
    STB4(0, pb0a, pb0b); STB4(1, pb1a, pb1b); STB4(2, pb2a, pb2b); STB4(3, pb3a, pb3b);
    __syncthreads();
    if (k0 + BK < kend) {                     // prefetch next tile into named registers
      k0n = k0 + BK;
      LDA4(0, pa0); LDA4(1, pa1); LDA4(2, pa2); LDA4(3, pa3);
      LDB4(0, pb0a, pb0b); LDB4(1, pb1a, pb1b); LDB4(2, pb2a, pb2b); LDB4(3, pb3a, pb3b);
    }
#pragma unroll
    for (int kk = 0; kk < BK; kk += 32) {
      bf16x8 af[FM], bfr[FN];
#pragma unroll
      for (int i = 0; i < FM; i++) {
        int rr = wm + i * 16 + frow;
        int ch = (kk >> 3) + cgrp;
        af[i] = *reinterpret_cast<const bf16x8*>(&As[rr * BK + ((ch ^ (rr & (GPB - 1))) << 3)]);
      }
#pragma unroll
      for (int j = 0; j < FN; j++) {
        int rr = wn + j * 16 + frow;
        int ch = (kk >> 3) + cgrp;
        bfr[j] = *reinterpret_cast<const bf16x8*>(&Bs[rr * BK + ((ch ^ (rr & (GPB - 1))) << 3)]);
      }
#pragma unroll
      for (int i = 0; i < FM; i++)
#pragma unroll
        for (int j = 0; j < FN; j++)
          acc[i][j] = __builtin_amdgcn_mfma_f32_16x16x32_bf16(af[i], bfr[j], acc[i][j], 0, 0, 0);
    }
    __syncthreads();
  }

  const int crow = (lane >> 4) * 4;
  const int ccol = lane & 15;
  if constexpr (EPI == 0) {
    float* Cz = C + (size_t)z * TOKENS * N;
#pragma unroll
    for (int i = 0; i < FM; i++)
#pragma unroll
      for (int j = 0; j < FN; j++) {
        int row = m0 + wm + i * 16 + crow;
        int col = n0 + wn + j * 16 + ccol;
#pragma unroll
        for (int r = 0; r < 4; r++)
          Cz[(size_t)(row + r) * N + col] = acc[i][j][r];
      }
  } else {
    const int ldXe = infOut * 9;
#pragma unroll
    for (int i = 0; i < FM; i++)
#pragma unroll
      for (int j = 0; j < FN; j++) {
        int row0 = m0 + wm + i * 16 + crow;
        int col = n0 + wn + j * 16 + ccol;
#pragma unroll
        for (int r = 0; r < 4; r++) {
          float y = fmaxf(acc[i][j][r], 0.0f);     // relu
          u16 s; us8 u;
          expand9(y, &s, &u);
          size_t base = (size_t)(row0 + r) * ldXe;
          XeOut[base + col] = s;
          *(us8*)(XeOut + base + infOut + (size_t)col * 8) = u;
        }
      }
  }
}

// ---------- fused attention: QK^T + softmax + PV + KAN-expand ----------
// qkv provided as 2 split-K partials (summed at load).

__global__ void attn_fused(const float* __restrict__ qkv, const float* __restrict__ qkv2,
                           u16* __restrict__ Xe) {
  int bh = blockIdx.x, b = bh >> 2, h = bh & 3;
  int s0 = blockIdx.y * 16;
  int t = threadIdx.x;
  __shared__ float Qs[16][64];
  __shared__ float Ks[16][65];
  __shared__ float Ss[16][513];
  __shared__ float red[16][17];
  __shared__ float Vs[32][65];
#pragma unroll
  for (int c = 0; c < 4; c++) {
    int e = c * 256 + t, r = e >> 6, d = e & 63;
    size_t ix = (size_t)(b * SEQ + s0 + r) * 768 + h * 64 + d;
    Qs[r][d] = qkv[ix] + qkv2[ix];
  }
  int r = t >> 4, cc = t & 15;
  for (int kc = 0; kc < SEQ; kc += 16) {
    __syncthreads();
#pragma unroll
    for (int c = 0; c < 4; c++) {
      int e = c * 256 + t, rr = e >> 6, d = e & 63;
      size_t ix = (size_t)(b * SEQ + kc + rr) * 768 + 256 + h * 64 + d;
      Ks[rr][d] = qkv[ix] + qkv2[ix];
    }
    __syncthreads();
    float acc = 0.f;
#pragma unroll
    for (int d = 0; d < 64; d++) acc += Qs[r][d] * Ks[cc][d];
    Ss[r][kc + cc] = acc * 0.125f;
  }
  __syncthreads();
  float mx = -3.4e38f;
  for (int j = cc; j < SEQ; j += 16) mx = fmaxf(mx, Ss[r][j]);
  red[r][cc] = mx;
  __syncthreads();
  if (cc == 0) {
    float m = red[r][0];
#pragma unroll
    for (int j = 1; j < 16; j++) m = fmaxf(m, red[r][j]);
    red[r][16] = m;
  }
  __syncthreads();
  mx = red[r][16];
  float sm = 0.f;
  for (int j = cc; j < SEQ; j += 16) {
    float e = expf(Ss[r][j] - mx);
    Ss[r][j] = e;
    sm += e;
  }
  __syncthreads();
  red[r][cc] = sm;
  __syncthreads();
  if (cc == 0) {
    float s = 0.f;
#pragma unroll
    for (int j = 0; j < 16; j++) s += red[r][j];
    red[r][16] = s;
  }
  __syncthreads();
  float inv = 1.0f / red[r][16];
  for (int j = cc; j < SEQ; j += 16) Ss[r][j] *= inv;
  // PV
  int dd = cc * 4;
  float a0 = 0.f, a1 = 0.f, a2 = 0.f, a3 = 0.f;
  for (int kc = 0; kc < SEQ; kc += 32) {
    __syncthreads();
#pragma unroll
    for (int c = 0; c < 8; c++) {
      int e = c * 256 + t, rr = e >> 6, d = e & 63;
      size_t ix = (size_t)(b * SEQ + kc + rr) * 768 + 512 + h * 64 + d;
      Vs[rr][d] = qkv[ix] + qkv2[ix];
    }
    __syncthreads();
#pragma unroll
    for (int kk = 0; kk < 32; kk++) {
      float p = Ss[r][kc + kk];
      a0 += p * Vs[kk][dd + 0];
      a1 += p * Vs[kk][dd + 1];
      a2 += p * Vs[kk][dd + 2];
      a3 += p * Vs[kk][dd + 3];
    }
  }
  int row = b * SEQ + s0 + r;
  size_t base = (size_t)row * 2304;
  float av[4] = {a0, a1, a2, a3};
#pragma unroll
  for (int j = 0; j < 4; j++) {
    int col = h * 64 + dd + j;
    u16 s; us8 u;
    expand9(av[j], &s, &u);
    Xe[base + col] = s;
    *(us8*)(Xe + base + 256 + (size_t)col * 8) = u;
  }
}

// ---------- launch ----------

extern "C" void kernel_launch(void* const* d_in, const int* in_sizes, int n_in,
                              void* d_out, int out_size, void* d_ws, size_t ws_size,
                              hipStream_t stream) {
  const int* ids = (const int*)d_in[0];
  const float* wemb = (const float*)d_in[1];
  const float* ttemb = (const float*)d_in[2];
  const float* pemb = (const float*)d_in[3];
  const float* elg = (const float*)d_in[4];
  const float* elb = (const float*)d_in[5];
  const float* qb = (const float*)d_in[6], *qs = (const float*)d_in[7];
  const float* kb = (const float*)d_in[8], *ks = (const float*)d_in[9];
  const float* vb = (const float*)d_in[10], *vs = (const float*)d_in[11];
  const float* ob = (const float*)d_in[12], *osp = (const float*)d_in[13];
  const float* f1b = (const float*)d_in[14], *f1s = (const float*)d_in[15];
  const float* f2b = (const float*)d_in[16], *f2s = (const float*)d_in[17];
  const float* l1g = (const float*)d_in[18], *l1b = (const float*)d_in[19];
  const float* l2g = (const float*)d_in[20], *l2b = (const float*)d_in[21];
  const float* hkb = (const float*)d_in[22], *hks = (const float*)d_in[23];
  const float* hob = (const float*)d_in[24], *hos = (const float*)d_in[25];
  float* out = (float*)d_out;

  char* w = (char*)d_ws;
  const size_t MB = 1 << 20;
  float* xbuf = (float*)(w);                 // 1 MB  [1024*256]
  float* tmp  = (float*)(w + 1 * MB);        // 1 MB  (head LN scratch)
  float* qkv  = (float*)(w + 2 * MB);        // 6 MB  [2][1024*768] split-K partials
  float* part = (float*)(w + 8 * MB);        // 8 MB  [8][1024*256] split-K partials
  u16*   Xe2  = (u16*)  (w + 16 * MB);       // 18 MB [1024*9216]   f1-out expansion
  u16*   Xe   = (u16*)  (w + 34 * MB);       // 4.5MB [1024*2304]

  embed_ln_x<<<TOKENS, 256, 0, stream>>>(ids, wemb, ttemb, pemb, elg, elb, xbuf, Xe);

  for (int l = 0; l < 4; l++) {
    const float* qbl = qb + (size_t)l * 65536, *qsl = qs + (size_t)l * 524288;
    const float* kbl = kb + (size_t)l * 65536, *ksl = ks + (size_t)l * 524288;
    const float* vbl = vb + (size_t)l * 65536, *vsl = vs + (size_t)l * 524288;
    const float* obl = ob + (size_t)l * 65536, *osl = osp + (size_t)l * 524288;
    const float* f1bl = f1b + (size_t)l * 262144, *f1sl = f1s + (size_t)l * 2097152;
    const float* f2bl = f2b + (size_t)l * 262144, *f2sl = f2s + (size_t)l * 2097152;

    gemm_kw<64, 64, 128, 2, 0><<<dim3(16, 12, 2), 256, 0, stream>>>(
        Xe, qbl, qsl, kbl, ksl, vbl, vsl, 256, 768, 2304, 256, 1152, qkv, nullptr, 0);
    attn_fused<<<dim3(8, 32), 256, 0, stream>>>(qkv, qkv + TOKENS * 768, Xe);
    gemm_kw<64, 64, 128, 2, 0><<<dim3(16, 4, 4), 256, 0, stream>>>(
        Xe, obl, osl, obl, osl, obl, osl, 256, 256, 2304, 256, 640, part, nullptr, 0);
    add_ln_x<<<TOKENS, 256, 0, stream>>>(part, 4, TOKENS * 256, xbuf,
                                         l1g + l * 256, l1b + l * 256, 1e-5f, 0, xbuf, Xe);
    gemm_kw<64, 64, 128, 2, 1><<<dim3(16, 16), 256, 0, stream>>>(
        Xe, f1bl, f1sl, f1bl, f1sl, f1bl, f1sl, 1024, 1024, 2304, 256, 2304,
        nullptr, Xe2, 1024);
    gemm_kw<64, 64, 128, 2, 0><<<dim3(16, 4, 8), 256, 0, stream>>>(
        Xe2, f2bl, f2sl, f2bl, f2sl, f2bl, f2sl, 256, 256, 9216, 1024, 1152,
        part, nullptr, 0);
    add_ln_x<<<TOKENS, 256, 0, stream>>>(part, 8, TOKENS * 256, xbuf,
                                         l2g + l * 256, l2b + l * 256, 1e-5f, 0, xbuf, Xe);
  }

  // head: KAN -> gelu -> LN(no affine, eps 1e-12) -> KAN to vocab
  gemm_kw<64, 64, 128, 2, 0><<<dim3(16, 4, 4), 256, 0, stream>>>(
      Xe, hkb, hks, hkb, hks, hkb, hks, 256, 256, 2304, 256, 640, part, nullptr, 0);
  add_ln_x<<<TOKENS, 256, 0, stream>>>(part, 4, TOKENS * 256, nullptr, nullptr, nullptr,
                                       1e-12f, 1, tmp, Xe);
  gemm_kw<128, 128, 64, 1, 0><<<dim3(8, 250), 256, 0, stream>>>(
      Xe, hob, hos, hob, hos, hob, hos, 32000, 32000, 2304, 256, 2304, out, nullptr, 0);
}

// Round 9
// 901.978 us; speedup vs baseline: 3.3546x; 1.1453x over previous
//
#include <hip/hip_runtime.h>
#include <math.h>

typedef unsigned short u16;
typedef unsigned int u32;
typedef __bf16 bf16x8 __attribute__((ext_vector_type(8)));
typedef float f32x4 __attribute__((ext_vector_type(4)));
typedef u16 us8 __attribute__((ext_vector_type(8)));

#define TOKENS 1024
#define DIM 256
#define SEQ 512

// ---------- helpers ----------

__device__ __forceinline__ u16 f2bf(float f) {
  u32 x = __float_as_uint(f);
  x += 0x7fffu + ((x >> 16) & 1u);
  return (u16)(x >> 16);
}

// silu + 8 cubic B-spline bases, uniform extended grid g[j] = (j-3)*0.4f - 1.0f.
// Compile-time-reciprocal Cox-de Boor (denominators constant).
__device__ __forceinline__ void expand9(float x, u16* sil, us8* u) {
  float sig = 1.0f / (1.0f + expf(-x));
  *sil = f2bf(x * sig);
  float bs[11];
#pragma unroll
  for (int j = 0; j < 11; j++) {
    float gj  = (float)(j - 3) * 0.4f - 1.0f;
    float gj1 = (float)(j - 2) * 0.4f - 1.0f;
    bs[j] = (x >= gj && x < gj1) ? 1.0f : 0.0f;
  }
#pragma unroll
  for (int k = 1; k <= 3; k++) {
#pragma unroll
    for (int j = 0; j < 10; j++) {
      if (j + k < 11) {
        float gj   = (float)(j - 3) * 0.4f - 1.0f;
        float gj1  = (float)(j - 2) * 0.4f - 1.0f;
        float gjk  = (float)(j + k - 3) * 0.4f - 1.0f;
        float gjk1 = (float)(j + k - 2) * 0.4f - 1.0f;
        float linv = 1.0f / (gjk - gj);
        float rinv = 1.0f / (gjk1 - gj1);
        bs[j] = (x - gj) * linv * bs[j] + (gjk1 - x) * rinv * bs[j + 1];
      }
    }
  }
#pragma unroll
  for (int c = 0; c < 8; c++) (*u)[c] = f2bf(bs[c]);
}

// 256-thread block sum (4 waves of 64)
__device__ __forceinline__ float block_sum_256(float v) {
  __shared__ float red[4];
  int t = threadIdx.x, lane = t & 63, wid = t >> 6;
#pragma unroll
  for (int o = 32; o > 0; o >>= 1) v += __shfl_down(v, o, 64);
  __syncthreads();
  if (lane == 0) red[wid] = v;
  __syncthreads();
  return red[0] + red[1] + red[2] + red[3];
}

// ---------- embedding + LN (eps 1e-12) + expand ----------

__global__ void embed_ln_x(const int* __restrict__ ids, const float* __restrict__ wemb,
                           const float* __restrict__ tt, const float* __restrict__ pe,
                           const float* __restrict__ g, const float* __restrict__ bta,
                           float* __restrict__ xout, u16* __restrict__ Xe) {
  int row = blockIdx.x, t = threadIdx.x;
  int id = ids[row];
  float v = wemb[(size_t)id * DIM + t] + tt[DIM + t] + pe[DIM + t];
  float mu = block_sum_256(v) * (1.0f / 256.0f);
  float d = v - mu;
  float var = block_sum_256(d * d) * (1.0f / 256.0f);
  float y = d * rsqrtf(var + 1e-12f) * g[t] + bta[t];
  xout[(size_t)row * DIM + t] = y;
  size_t base = (size_t)row * 2304;
  u16 s; us8 u;
  expand9(y, &s, &u);
  Xe[base + t] = s;
  *(us8*)(Xe + base + 256 + (size_t)t * 8) = u;
}

// ---------- (sum of nsum partials) [+gelu] [+res] + LN + expand ----------

__global__ void add_ln_x(const float* __restrict__ a, int nsum, int sstride,
                         const float* __restrict__ res,
                         const float* __restrict__ g, const float* __restrict__ bta,
                         float eps, int dogelu,
                         float* __restrict__ xout, u16* __restrict__ Xe) {
  int row = blockIdx.x, t = threadIdx.x;
  int idx = row * 256 + t;
  float v = 0.f;
  for (int s = 0; s < nsum; s++) v += a[(size_t)s * sstride + idx];
  if (dogelu) v = 0.5f * v * (1.0f + erff(v * 0.70710678118654752f));
  if (res) v += res[idx];
  float mu = block_sum_256(v) * (1.0f / 256.0f);
  float d = v - mu;
  float var = block_sum_256(d * d) * (1.0f / 256.0f);
  float y = d * rsqrtf(var + eps);
  if (g) y = y * g[t] + bta[t];
  xout[idx] = y;
  size_t base = (size_t)row * 2304;
  u16 s16; us8 u;
  expand9(y, &s16, &u);
  Xe[base + t] = s16;
  *(us8*)(Xe + base + 256 + (size_t)t * 8) = u;
}

// ---------- GEMM: C[1024,N] = A[1024,K](bf16) @ Wvirt[N,K]^T, W = [base|spline] f32 ----------
// f32 weights converted RNE->bf16 during staging. XCD-contiguous remap, XOR-swizzled
// LDS, named-register prefetch pipeline. blockIdx.z = K-split slice (kchunk, multiple
// of BK); partial C at z*TOKENS*N. EPI: 0 = f32 store; 1 = relu+KAN-expand into XeOut.

#define LDA4(c, v) { int r_ = (c) * RPC + (t >> LGP); int g_ = t & (GPB - 1); \
    v = *(const uint4*)(A + (size_t)(m0 + r_) * K + k0n + g_ * 8); }
#define LDB4(c, va, vb) { int r_ = (c) * RPC + (t >> LGP); int g_ = t & (GPB - 1); \
    int kv_ = k0n + g_ * 8; \
    const float* p_ = (kv_ < infeat) ? (Wb + (size_t)(onb + r_) * infeat + kv_) \
                                     : (Ws + (size_t)(onb + r_) * infeat * 8 + (kv_ - infeat)); \
    va = *(const float4*)p_; vb = *(const float4*)(p_ + 4); }
#define STA4(c, v) { int r_ = (c) * RPC + (t >> LGP); int g_ = t & (GPB - 1); \
    *(uint4*)(&As[r_ * BK + ((g_ ^ (r_ & (GPB - 1))) << 3)]) = v; }
#define STB4(c, va, vb) { int r_ = (c) * RPC + (t >> LGP); int g_ = t & (GPB - 1); \
    bf16x8 h_; \
    h_[0] = (__bf16)va.x; h_[1] = (__bf16)va.y; h_[2] = (__bf16)va.z; h_[3] = (__bf16)va.w; \
    h_[4] = (__bf16)vb.x; h_[5] = (__bf16)vb.y; h_[6] = (__bf16)vb.z; h_[7] = (__bf16)vb.w; \
    *(bf16x8*)(&Bs[r_ * BK + ((g_ ^ (r_ & (GPB - 1))) << 3)]) = h_; }

template <int BM, int BN, int BK, int MINW, int EPI>
__global__ __launch_bounds__(256, MINW)
void gemm_kw(const u16* __restrict__ A,
             const float* __restrict__ b0, const float* __restrict__ s0,
             const float* __restrict__ b1, const float* __restrict__ s1,
             const float* __restrict__ b2, const float* __restrict__ s2,
             int nper, int N, int K, int infeat, int kchunk, float* __restrict__ C,
             u16* __restrict__ XeOut, int infOut) {
  constexpr int GPB = BK / 8;                // 8-col groups per row
  constexpr int LGP = (GPB == 8) ? 3 : 4;
  constexpr int RPC = 256 / GPB;             // rows per staging chunk
  static_assert(BM / RPC == 4 && BN / RPC == 4, "need exactly 4+4 chunks");
  constexpr int FM = BM / 32, FN = BN / 32;
  __shared__ u16 As[BM * BK];
  __shared__ u16 Bs[BN * BK];
  const int gx = gridDim.x;
  const int nwg = gx * gridDim.y;
  int g = blockIdx.y * gx + blockIdx.x;
  int lin = g;
  if ((nwg & 7) == 0) lin = (g & 7) * (nwg >> 3) + (g >> 3);
  const int m0 = (lin % gx) * BM;
  const int n0 = (lin / gx) * BN;
  const int z = blockIdx.z;
  const int kbeg = z * kchunk;
  const int kend = (kbeg + kchunk < K) ? kbeg + kchunk : K;
  const int t = threadIdx.x;
  const int lane = t & 63, wid = t >> 6;
  const int wm = (wid >> 1) * (BM / 2), wn = (wid & 1) * (BN / 2);
  const int proj = n0 / nper;
  const float* Wb = proj == 0 ? b0 : (proj == 1 ? b1 : b2);
  const float* Ws = proj == 0 ? s0 : (proj == 1 ? s1 : s2);
  const int onb = n0 - proj * nper;

  f32x4 acc[FM][FN];
#pragma unroll
  for (int i = 0; i < FM; i++)
#pragma unroll
    for (int j = 0; j < FN; j++) acc[i][j] = (f32x4){0.f, 0.f, 0.f, 0.f};

  const int frow = lane & 15;
  const int cgrp = lane >> 4;

  uint4 pa0, pa1, pa2, pa3;
  float4 pb0a, pb0b, pb1a, pb1b, pb2a, pb2b, pb3a, pb3b;
  int k0n = kbeg;
  LDA4(0, pa0); LDA4(1, pa1); LDA4(2, pa2); LDA4(3, pa3);
  LDB4(0, pb0a, pb0b); LDB4(1, pb1a, pb1b); LDB4(2, pb2a, pb2b); LDB4(3, pb3a, pb3b);

  for (int k0 = kbeg; k0 < kend; k0 += BK) {
    STA4(0, pa0); STA4(1, pa1); STA4(2, pa2); STA4(3, pa3);
    STB4(0, pb0a, pb0b); STB4(1, pb1a, pb1b); STB4(2, pb2a, pb2b); STB4(3, pb3a, pb3b);
    __syncthreads();
    if (k0 + BK < kend) {                     // prefetch next tile into named registers
      k0n = k0 + BK;
      LDA4(0, pa0); LDA4(1, pa1); LDA4(2, pa2); LDA4(3, pa3);
      LDB4(0, pb0a, pb0b); LDB4(1, pb1a, pb1b); LDB4(2, pb2a, pb2b); LDB4(3, pb3a, pb3b);
    }
#pragma unroll
    for (int kk = 0; kk < BK; kk += 32) {
      bf16x8 af[FM], bfr[FN];
#pragma unroll
      for (int i = 0; i < FM; i++) {
        int rr = wm + i * 16 + frow;
        int ch = (kk >> 3) + cgrp;
        af[i] = *reinterpret_cast<const bf16x8*>(&As[rr * BK + ((ch ^ (rr & (GPB - 1))) << 3)]);
      }
#pragma unroll
      for (int j = 0; j < FN; j++) {
        int rr = wn + j * 16 + frow;
        int ch = (kk >> 3) + cgrp;
        bfr[j] = *reinterpret_cast<const bf16x8*>(&Bs[rr * BK + ((ch ^ (rr & (GPB - 1))) << 3)]);
      }
#pragma unroll
      for (int i = 0; i < FM; i++)
#pragma unroll
        for (int j = 0; j < FN; j++)
          acc[i][j] = __builtin_amdgcn_mfma_f32_16x16x32_bf16(af[i], bfr[j], acc[i][j], 0, 0, 0);
    }
    __syncthreads();
  }

  const int crow = (lane >> 4) * 4;
  const int ccol = lane & 15;
  if constexpr (EPI == 0) {
    float* Cz = C + (size_t)z * TOKENS * N;
#pragma unroll
    for (int i = 0; i < FM; i++)
#pragma unroll
      for (int j = 0; j < FN; j++) {
        int row = m0 + wm + i * 16 + crow;
        int col = n0 + wn + j * 16 + ccol;
#pragma unroll
        for (int r = 0; r < 4; r++)
          Cz[(size_t)(row + r) * N + col] = acc[i][j][r];
      }
  } else {
    const int ldXe = infOut * 9;
#pragma unroll
    for (int i = 0; i < FM; i++)
#pragma unroll
      for (int j = 0; j < FN; j++) {
        int row0 = m0 + wm + i * 16 + crow;
        int col = n0 + wn + j * 16 + ccol;
#pragma unroll
        for (int r = 0; r < 4; r++) {
          float y = fmaxf(acc[i][j][r], 0.0f);     // relu
          u16 s; us8 u;
          expand9(y, &s, &u);
          size_t base = (size_t)(row0 + r) * ldXe;
          XeOut[base + col] = s;
          *(us8*)(XeOut + base + infOut + (size_t)col * 8) = u;
        }
      }
  }
}

// ---------- fused attention: QK^T + softmax + PV + KAN-expand ----------
// qkv provided as 3 split-K partials (summed at load); partial stride = TOKENS*768.

__global__ void attn_fused(const float* __restrict__ qkv, u16* __restrict__ Xe) {
  const float* q1 = qkv + (size_t)TOKENS * 768;
  const float* q2 = qkv + (size_t)2 * TOKENS * 768;
  int bh = blockIdx.x, b = bh >> 2, h = bh & 3;
  int s0 = blockIdx.y * 16;
  int t = threadIdx.x;
  __shared__ float Qs[16][64];
  __shared__ float Ks[16][65];
  __shared__ float Ss[16][513];
  __shared__ float red[16][17];
  __shared__ float Vs[32][65];
#pragma unroll
  for (int c = 0; c < 4; c++) {
    int e = c * 256 + t, r = e >> 6, d = e & 63;
    size_t ix = (size_t)(b * SEQ + s0 + r) * 768 + h * 64 + d;
    Qs[r][d] = qkv[ix] + q1[ix] + q2[ix];
  }
  int r = t >> 4, cc = t & 15;
  for (int kc = 0; kc < SEQ; kc += 16) {
    __syncthreads();
#pragma unroll
    for (int c = 0; c < 4; c++) {
      int e = c * 256 + t, rr = e >> 6, d = e & 63;
      size_t ix = (size_t)(b * SEQ + kc + rr) * 768 + 256 + h * 64 + d;
      Ks[rr][d] = qkv[ix] + q1[ix] + q2[ix];
    }
    __syncthreads();
    float acc = 0.f;
#pragma unroll
    for (int d = 0; d < 64; d++) acc += Qs[r][d] * Ks[cc][d];
    Ss[r][kc + cc] = acc * 0.125f;
  }
  __syncthreads();
  float mx = -3.4e38f;
  for (int j = cc; j < SEQ; j += 16) mx = fmaxf(mx, Ss[r][j]);
  red[r][cc] = mx;
  __syncthreads();
  if (cc == 0) {
    float m = red[r][0];
#pragma unroll
    for (int j = 1; j < 16; j++) m = fmaxf(m, red[r][j]);
    red[r][16] = m;
  }
  __syncthreads();
  mx = red[r][16];
  float sm = 0.f;
  for (int j = cc; j < SEQ; j += 16) {
    float e = expf(Ss[r][j] - mx);
    Ss[r][j] = e;
    sm += e;
  }
  __syncthreads();
  red[r][cc] = sm;
  __syncthreads();
  if (cc == 0) {
    float s = 0.f;
#pragma unroll
    for (int j = 0; j < 16; j++) s += red[r][j];
    red[r][16] = s;
  }
  __syncthreads();
  float inv = 1.0f / red[r][16];
  for (int j = cc; j < SEQ; j += 16) Ss[r][j] *= inv;
  // PV
  int dd = cc * 4;
  float a0 = 0.f, a1 = 0.f, a2 = 0.f, a3 = 0.f;
  for (int kc = 0; kc < SEQ; kc += 32) {
    __syncthreads();
#pragma unroll
    for (int c = 0; c < 8; c++) {
      int e = c * 256 + t, rr = e >> 6, d = e & 63;
      size_t ix = (size_t)(b * SEQ + kc + rr) * 768 + 512 + h * 64 + d;
      Vs[rr][d] = qkv[ix] + q1[ix] + q2[ix];
    }
    __syncthreads();
#pragma unroll
    for (int kk = 0; kk < 32; kk++) {
      float p = Ss[r][kc + kk];
      a0 += p * Vs[kk][dd + 0];
      a1 += p * Vs[kk][dd + 1];
      a2 += p * Vs[kk][dd + 2];
      a3 += p * Vs[kk][dd + 3];
    }
  }
  int row = b * SEQ + s0 + r;
  size_t base = (size_t)row * 2304;
  float av[4] = {a0, a1, a2, a3};
#pragma unroll
  for (int j = 0; j < 4; j++) {
    int col = h * 64 + dd + j;
    u16 s; us8 u;
    expand9(av[j], &s, &u);
    Xe[base + col] = s;
    *(us8*)(Xe + base + 256 + (size_t)col * 8) = u;
  }
}

// ---------- launch ----------

extern "C" void kernel_launch(void* const* d_in, const int* in_sizes, int n_in,
                              void* d_out, int out_size, void* d_ws, size_t ws_size,
                              hipStream_t stream) {
  const int* ids = (const int*)d_in[0];
  const float* wemb = (const float*)d_in[1];
  const float* ttemb = (const float*)d_in[2];
  const float* pemb = (const float*)d_in[3];
  const float* elg = (const float*)d_in[4];
  const float* elb = (const float*)d_in[5];
  const float* qb = (const float*)d_in[6], *qs = (const float*)d_in[7];
  const float* kb = (const float*)d_in[8], *ks = (const float*)d_in[9];
  const float* vb = (const float*)d_in[10], *vs = (const float*)d_in[11];
  const float* ob = (const float*)d_in[12], *osp = (const float*)d_in[13];
  const float* f1b = (const float*)d_in[14], *f1s = (const float*)d_in[15];
  const float* f2b = (const float*)d_in[16], *f2s = (const float*)d_in[17];
  const float* l1g = (const float*)d_in[18], *l1b = (const float*)d_in[19];
  const float* l2g = (const float*)d_in[20], *l2b = (const float*)d_in[21];
  const float* hkb = (const float*)d_in[22], *hks = (const float*)d_in[23];
  const float* hob = (const float*)d_in[24], *hos = (const float*)d_in[25];
  float* out = (float*)d_out;

  char* w = (char*)d_ws;
  const size_t MB = 1 << 20;
  float* xbuf = (float*)(w);                 // 1 MB  [1024*256]
  float* tmp  = (float*)(w + 1 * MB);        // 1 MB  (head LN scratch)
  float* qkv  = (float*)(w + 2 * MB);        // 9 MB  [3][1024*768] split-K partials
  float* part = (float*)(w + 11 * MB);       // 9 MB  [9][1024*256] split-K partials
  u16*   Xe2  = (u16*)  (w + 20 * MB);       // 18 MB [1024*9216]   f1-out expansion
  u16*   Xe   = (u16*)  (w + 38 * MB);       // 4.5MB [1024*2304]

  embed_ln_x<<<TOKENS, 256, 0, stream>>>(ids, wemb, ttemb, pemb, elg, elb, xbuf, Xe);

  for (int l = 0; l < 4; l++) {
    const float* qbl = qb + (size_t)l * 65536, *qsl = qs + (size_t)l * 524288;
    const float* kbl = kb + (size_t)l * 65536, *ksl = ks + (size_t)l * 524288;
    const float* vbl = vb + (size_t)l * 65536, *vsl = vs + (size_t)l * 524288;
    const float* obl = ob + (size_t)l * 65536, *osl = osp + (size_t)l * 524288;
    const float* f1bl = f1b + (size_t)l * 262144, *f1sl = f1s + (size_t)l * 2097152;
    const float* f2bl = f2b + (size_t)l * 262144, *f2sl = f2s + (size_t)l * 2097152;

    // qkv: split-K x3 (576 blocks, 6 iters/slice)
    gemm_kw<64, 64, 128, 2, 0><<<dim3(16, 12, 3), 256, 0, stream>>>(
        Xe, qbl, qsl, kbl, ksl, vbl, vsl, 256, 768, 2304, 256, 768, qkv, nullptr, 0);
    attn_fused<<<dim3(8, 32), 256, 0, stream>>>(qkv, Xe);
    // o-proj: split-K x9 (576 blocks, 2 iters/slice)
    gemm_kw<64, 64, 128, 2, 0><<<dim3(16, 4, 9), 256, 0, stream>>>(
        Xe, obl, osl, obl, osl, obl, osl, 256, 256, 2304, 256, 256, part, nullptr, 0);
    add_ln_x<<<TOKENS, 256, 0, stream>>>(part, 9, TOKENS * 256, xbuf,
                                         l1g + l * 256, l1b + l * 256, 1e-5f, 0, xbuf, Xe);
    // f1: fused relu+expand epilogue (no split-K possible), 256 blocks
    gemm_kw<64, 64, 128, 2, 1><<<dim3(16, 16), 256, 0, stream>>>(
        Xe, f1bl, f1sl, f1bl, f1sl, f1bl, f1sl, 1024, 1024, 2304, 256, 2304,
        nullptr, Xe2, 1024);
    // f2: split-K x8 (512 blocks, 9 iters/slice)
    gemm_kw<64, 64, 128, 2, 0><<<dim3(16, 4, 8), 256, 0, stream>>>(
        Xe2, f2bl, f2sl, f2bl, f2sl, f2bl, f2sl, 256, 256, 9216, 1024, 1152,
        part, nullptr, 0);
    add_ln_x<<<TOKENS, 256, 0, stream>>>(part, 8, TOKENS * 256, xbuf,
                                         l2g + l * 256, l2b + l * 256, 1e-5f, 0, xbuf, Xe);
  }

  // head: KAN -> gelu -> LN(no affine, eps 1e-12) -> KAN to vocab
  gemm_kw<64, 64, 128, 2, 0><<<dim3(16, 4, 9), 256, 0, stream>>>(
      Xe, hkb, hks, hkb, hks, hkb, hks, 256, 256, 2304, 256, 256, part, nullptr, 0);
  add_ln_x<<<TOKENS, 256, 0, stream>>>(part, 9, TOKENS * 256, nullptr, nullptr, nullptr,
                                       1e-12f, 1, tmp, Xe);
  gemm_kw<128, 128, 64, 1, 0><<<dim3(8, 250), 256, 0, stream>>>(
      Xe, hob, hos, hob, hos, hob, hos, 32000, 32000, 2304, 256, 2304, out, nullptr, 0);
}